// Round 1
// baseline (704.779 us; speedup 1.0000x reference)
//
#include <hip/hip_runtime.h>
#include <math.h>

#define DIN  512
#define DOUT 512
#define CHK  64
#define NCH  64
#define NB   8
#define SEQ  4096

__device__ __forceinline__ float sigmoidf_(float z){ return 1.0f/(1.0f+__expf(-z)); }

// ---------------- K1: per-(batch,chunk) statistics ----------------
// Computes KM (k_mean), Dv (xbar - k_mean), c1 = gate*alpha+1-gate, c2 = gate*eta, km2 = ||k_mean||^2
__global__ __launch_bounds__(256) void k1_stats(
    const float* __restrict__ x,
    const float* __restrict__ eta_w, const float* __restrict__ eta_b,
    const float* __restrict__ alpha_w, const float* __restrict__ alpha_b,
    const float* __restrict__ gate_w, const float* __restrict__ gate_b,
    float* __restrict__ KM, float* __restrict__ Dv,
    float* __restrict__ C1, float* __restrict__ C2, float* __restrict__ KM2)
{
  int j = blockIdx.x, b = blockIdx.y;
  const float* xc = x + ((size_t)b*SEQ + (size_t)j*CHK) * DIN;
  int tid = threadIdx.x;
  int wave = tid >> 6, lane = tid & 63;

  float km_acc[8], xb_acc[8];
#pragma unroll
  for (int k=0;k<8;k++){ km_acc[k]=0.f; xb_acc[k]=0.f; }
  float eta_sum = 0.f, alpha_sum = 0.f;
  float ew[8], aw[8];
#pragma unroll
  for (int k=0;k<8;k++){ ew[k]=eta_w[lane*8+k]; aw[k]=alpha_w[lane*8+k]; }

  // each wave handles 16 tokens; lane owns dims [lane*8, lane*8+8)
  for (int tt=0; tt<16; tt++){
    int t = wave*16 + tt;
    const float* xr = xc + (size_t)t*DIN + lane*8;
    float v[8];
#pragma unroll
    for (int k=0;k<8;k++) v[k]=xr[k];
    float pe=0.f, pa=0.f, pn=0.f;
#pragma unroll
    for (int k=0;k<8;k++){ pe += v[k]*ew[k]; pa += v[k]*aw[k]; pn += v[k]*v[k]; }
#pragma unroll
    for (int off=32; off; off>>=1){
      pe += __shfl_xor(pe, off);
      pa += __shfl_xor(pa, off);
      pn += __shfl_xor(pn, off);
    }
    float inv = 1.0f / fmaxf(sqrtf(pn), 1e-5f);
    eta_sum   += sigmoidf_(pe + eta_b[0]);
    alpha_sum += sigmoidf_(pa + alpha_b[0]);
#pragma unroll
    for (int k=0;k<8;k++){ km_acc[k] += v[k]*inv; xb_acc[k] += v[k]; }
  }

  __shared__ float sKM[4][DIN];
  __shared__ float sXB[4][DIN];
  __shared__ float sEA[4][2];
  __shared__ float sred[4][2];
#pragma unroll
  for (int k=0;k<8;k++){ sKM[wave][lane*8+k]=km_acc[k]; sXB[wave][lane*8+k]=xb_acc[k]; }
  if (lane==0){ sEA[wave][0]=eta_sum; sEA[wave][1]=alpha_sum; }
  __syncthreads();

  float gpart=0.f, km2part=0.f;
  float kmv[2], dvv[2];
#pragma unroll
  for (int k=0;k<2;k++){
    int d = tid*2+k;
    float km = (sKM[0][d]+sKM[1][d]+sKM[2][d]+sKM[3][d]) * (1.0f/64.0f);
    float xb = (sXB[0][d]+sXB[1][d]+sXB[2][d]+sXB[3][d]) * (1.0f/64.0f);
    kmv[k]=km; dvv[k]=xb-km;
    gpart  += km * gate_w[d];
    km2part+= km * km;
  }
#pragma unroll
  for (int off=32; off; off>>=1){
    gpart   += __shfl_xor(gpart, off);
    km2part += __shfl_xor(km2part, off);
  }
  if (lane==0){ sred[wave][0]=gpart; sred[wave][1]=km2part; }
  __syncthreads();

  size_t base = ((size_t)b*NCH + j)*DIN;
#pragma unroll
  for (int k=0;k<2;k++){
    int d = tid*2+k;
    KM[base+d]=kmv[k];
    Dv[base+d]=dvv[k];
  }
  if (tid==0){
    float gdot = sred[0][0]+sred[1][0]+sred[2][0]+sred[3][0];
    float km2  = sred[0][1]+sred[1][1]+sred[2][1]+sred[3][1];
    float etam = (sEA[0][0]+sEA[1][0]+sEA[2][0]+sEA[3][0]) * (1.0f/64.0f);
    float alpm = (sEA[0][1]+sEA[1][1]+sEA[2][1]+sEA[3][1]) * (1.0f/64.0f);
    float eta   = 0.2f * etam;               // MAX_LR * mean(sigmoid)
    float alpha = 0.5f + 0.5f * alpm;        // MIN_DECAY + sig*(1-MIN_DECAY)
    float gate  = sigmoidf_(gdot + gate_b[0]);
    C1[b*NCH+j]  = gate*alpha + 1.0f - gate;
    C2[b*NCH+j]  = gate*eta;
    KM2[b*NCH+j] = km2;
  }
}

// ---------------- K2: G0 = D @ M0^T, H0 = KM @ M0^T (per b,j) ----------------
__global__ __launch_bounds__(256) void k2_g0h0(
    const float* __restrict__ KM, const float* __restrict__ Dv,
    const float* __restrict__ M0, float* __restrict__ G0, float* __restrict__ H0)
{
  int j = blockIdx.x, b = blockIdx.y;
  __shared__ float sD[DIN], sK[DIN];
  int tid = threadIdx.x;
  size_t base = ((size_t)b*NCH+j)*DIN;
  for (int d=tid; d<DIN; d+=256){ sD[d]=Dv[base+d]; sK[d]=KM[base+d]; }
  __syncthreads();
  for (int o=tid; o<DOUT; o+=256){
    const float* mr = M0 + (size_t)o*DIN;
    float ag=0.f, ah=0.f;
    for (int d=0; d<DIN; d+=4){
      float4 m = *(const float4*)(mr+d);
      ag += m.x*sD[d] + m.y*sD[d+1] + m.z*sD[d+2] + m.w*sD[d+3];
      ah += m.x*sK[d] + m.y*sK[d+1] + m.z*sK[d+2] + m.w*sK[d+3];
    }
    G0[base+o]=ag; H0[base+o]=ah;
  }
}

// ---------------- K2b: Gram matrices KMD[i][j]=km_i.d_j, KMKM[i][j]=km_i.km_j ----------------
__global__ __launch_bounds__(256) void k2b_gram(
    const float* __restrict__ KM, const float* __restrict__ Dv,
    float* __restrict__ KMD, float* __restrict__ KMKM)
{
  int i = blockIdx.x, b = blockIdx.y;
  __shared__ float sKi[DIN];
  int tid = threadIdx.x;
  const float* kmi = KM + ((size_t)b*NCH+i)*DIN;
  for (int d=tid; d<DIN; d+=256) sKi[d]=kmi[d];
  __syncthreads();
  int wave = tid>>6, lane = tid&63;
  for (int j=wave; j<NCH; j+=4){
    const float* dj = Dv + ((size_t)b*NCH+j)*DIN;
    const float* kj = KM + ((size_t)b*NCH+j)*DIN;
    float pd=0.f, pk=0.f;
#pragma unroll
    for (int k=0;k<8;k++){
      int d = lane + k*64;
      pd += sKi[d]*dj[d];
      pk += sKi[d]*kj[d];
    }
#pragma unroll
    for (int off=32; off; off>>=1){ pd += __shfl_xor(pd,off); pk += __shfl_xor(pk,off); }
    if (lane==0){
      KMD [((size_t)b*NCH+i)*NCH + j] = pd;
      KMKM[((size_t)b*NCH+i)*NCH + j] = pk;
    }
  }
}

// ---------------- K3: sequential vector recursion (one block per batch) ----------------
// u_j = p_j*(G0[j] + sum_{i<j} r_i*KMD[i,j]*u_i) ; w_j likewise with H0/KMKM
// Fnew = c1^2 F + 2 c1 c2 (u.w) + c2^2 ||u||^2 km2 ; scale = min(30/(sqrt(Fnew)+1e-6),1)
// p_{j+1} = scale*c1*p_j ; r_j = c2/(c1*p_j)
__global__ __launch_bounds__(512) void k3_scan(
    const float* __restrict__ M0,
    const float* __restrict__ G0, const float* __restrict__ H0,
    const float* __restrict__ KMD, const float* __restrict__ KMKM,
    const float* __restrict__ C1, const float* __restrict__ C2, const float* __restrict__ KM2,
    float* __restrict__ U, float* __restrict__ P, float* __restrict__ R)
{
  int b = blockIdx.x;
  int tid = threadIdx.x;          // one thread per output dim o
  int wave = tid>>6, lane = tid&63;
  __shared__ float sp[NCH+1];
  __shared__ float sr[NCH];
  __shared__ float scu[NCH], scw[NCH];
  __shared__ float sredu[8], sredw[8];

  // F0 = ||M0||^2 (redundant per block; M0 is L2-resident)
  float f0p = 0.f;
  const float4* m4 = (const float4*)M0;
  for (int idx = tid; idx < (DOUT*DIN)/4; idx += 512){
    float4 v = m4[idx];
    f0p += v.x*v.x + v.y*v.y + v.z*v.z + v.w*v.w;
  }
#pragma unroll
  for (int off=32; off; off>>=1) f0p += __shfl_xor(f0p, off);
  if (lane==0) sredu[wave]=f0p;
  __syncthreads();
  float F = 0.f;
  if (tid==0){
    for (int w2=0;w2<8;w2++) F += sredu[w2];
    sp[0]=1.0f;
  }
  __syncthreads();

  float* Ub = U + (size_t)b*NCH*DOUT;
  for (int j=0; j<NCH; j++){
    if (tid < j){
      float r = sr[tid];
      scu[tid] = r * KMD [((size_t)b*NCH+tid)*NCH + j];
      scw[tid] = r * KMKM[((size_t)b*NCH+tid)*NCH + j];
    }
    __syncthreads();
    size_t gbase = ((size_t)b*NCH+j)*DIN;
    float au = G0[gbase + tid];
    float aw = H0[gbase + tid];
    for (int i=0;i<j;i++){
      float ui = Ub[(size_t)i*DOUT + tid];
      au += scu[i]*ui;
      aw += scw[i]*ui;
    }
    float p = sp[j];
    float u = p*au, w = p*aw;
    Ub[(size_t)j*DOUT + tid] = u;
    float s1 = u*w, s2 = u*u;
#pragma unroll
    for (int off=32; off; off>>=1){ s1+=__shfl_xor(s1,off); s2+=__shfl_xor(s2,off); }
    if (lane==0){ sredu[wave]=s1; sredw[wave]=s2; }
    __syncthreads();
    if (tid==0){
      float uw=0.f, uu=0.f;
      for (int w2=0;w2<8;w2++){ uw+=sredu[w2]; uu+=sredw[w2]; }
      float c1 = C1[b*NCH+j], c2 = C2[b*NCH+j], km2 = KM2[b*NCH+j];
      float Fnew = c1*c1*F + 2.f*c1*c2*uw + c2*c2*uu*km2;
      float scale = fminf(30.0f/(sqrtf(Fnew)+1e-6f), 1.0f);
      F = scale*scale*Fnew;
      sp[j+1] = scale*c1*p;
      sr[j]   = c2/(c1*p);
    }
    __syncthreads();
  }
  if (tid <= NCH) P[b*(NCH+1)+tid] = sp[tid];
  if (tid <  NCH) R[b*NCH+tid]     = sr[tid];
}

// ---------------- K4s: S[b][t][i] = x_t . km_i ----------------
__global__ __launch_bounds__(256) void k4s_s(
    const float* __restrict__ x, const float* __restrict__ KM, float* __restrict__ S)
{
  int tt = blockIdx.x, b = blockIdx.y;
  int tid = threadIdx.x;
  __shared__ float Xs[64][68];
  __shared__ float Ks[64][68];
  float acc[4][4];
#pragma unroll
  for (int a=0;a<4;a++)
#pragma unroll
    for (int c=0;c<4;c++) acc[a][c]=0.f;
  int ty = tid & 15, tx = tid >> 4;
  int lt = tid >> 2, dq = tid & 3;
  for (int dt=0; dt<8; dt++){
    const float* xr = x  + ((size_t)b*SEQ + (size_t)tt*64 + lt)*DIN + dt*64 + dq*16;
    const float* kr = KM + ((size_t)b*NCH + lt)*DIN + dt*64 + dq*16;
    float4 xv0=*(const float4*)(xr),   xv1=*(const float4*)(xr+4);
    float4 xv2=*(const float4*)(xr+8), xv3=*(const float4*)(xr+12);
    float4 kv0=*(const float4*)(kr),   kv1=*(const float4*)(kr+4);
    float4 kv2=*(const float4*)(kr+8), kv3=*(const float4*)(kr+12);
    __syncthreads();
    *(float4*)&Xs[lt][dq*16+ 0]=xv0; *(float4*)&Xs[lt][dq*16+ 4]=xv1;
    *(float4*)&Xs[lt][dq*16+ 8]=xv2; *(float4*)&Xs[lt][dq*16+12]=xv3;
    *(float4*)&Ks[lt][dq*16+ 0]=kv0; *(float4*)&Ks[lt][dq*16+ 4]=kv1;
    *(float4*)&Ks[lt][dq*16+ 8]=kv2; *(float4*)&Ks[lt][dq*16+12]=kv3;
    __syncthreads();
#pragma unroll 8
    for (int dd=0; dd<64; dd++){
      float a0=Xs[ty][dd], a1=Xs[ty+16][dd], a2=Xs[ty+32][dd], a3=Xs[ty+48][dd];
      float b0=Ks[tx][dd], b1=Ks[tx+16][dd], b2=Ks[tx+32][dd], b3=Ks[tx+48][dd];
      acc[0][0]+=a0*b0; acc[0][1]+=a0*b1; acc[0][2]+=a0*b2; acc[0][3]+=a0*b3;
      acc[1][0]+=a1*b0; acc[1][1]+=a1*b1; acc[1][2]+=a1*b2; acc[1][3]+=a1*b3;
      acc[2][0]+=a2*b0; acc[2][1]+=a2*b1; acc[2][2]+=a2*b2; acc[2][3]+=a2*b3;
      acc[3][0]+=a3*b0; acc[3][1]+=a3*b1; acc[3][2]+=a3*b2; acc[3][3]+=a3*b3;
    }
  }
#pragma unroll
  for (int a=0;a<4;a++)
#pragma unroll
    for (int c=0;c<4;c++)
      S[((size_t)b*SEQ + (size_t)tt*64 + ty+16*a)*NCH + tx+16*c] = acc[a][c];
}

// ---------------- K4: out = p_j*(chunk@M0^T + sum_{i<j} r_i S[t,i] u_i^T) ----------------
__global__ __launch_bounds__(256) void k4_out(
    const float* __restrict__ x, const float* __restrict__ M0,
    const float* __restrict__ S, const float* __restrict__ U,
    const float* __restrict__ P, const float* __restrict__ R,
    float* __restrict__ out)
{
  int ot = blockIdx.x;       // 4 o-tiles of 128
  int j  = blockIdx.y;       // chunk
  int b  = blockIdx.z;
  int tid = threadIdx.x;
  int ty = tid & 15, tx = tid >> 4;
  int O0 = ot*128;
  __shared__ float As[16][64];
  __shared__ float Bs[16][128];
  __shared__ float Ss[64][65];
  __shared__ float Us[64][128];
  __shared__ float rs[64];
  float acc[4][8];
#pragma unroll
  for (int k=0;k<4;k++)
#pragma unroll
    for (int l=0;l<8;l++) acc[k][l]=0.f;

  // stage S tile, U tile, r
  {
    int t = tid>>2, iq = tid&3;
    const float* sp_ = S + ((size_t)b*SEQ + (size_t)j*64 + t)*NCH + iq*16;
#pragma unroll
    for (int k2=0;k2<16;k2++) Ss[t][iq*16+k2] = sp_[k2];
  }
  for (int idx=tid; idx<64*128; idx+=256){
    int i = idx>>7, ol = idx&127;
    Us[i][ol] = U[((size_t)b*NCH+i)*DOUT + O0 + ol];
  }
  if (tid<64) rs[tid] = R[b*NCH+tid];
  __syncthreads();

  // correction term
  for (int i=0;i<j;i++){
    float rv = rs[i];
    float sv0 = Ss[ty   ][i]*rv;
    float sv1 = Ss[ty+16][i]*rv;
    float sv2 = Ss[ty+32][i]*rv;
    float sv3 = Ss[ty+48][i]*rv;
    float4 u0 = *(const float4*)&Us[i][tx*8];
    float4 u1 = *(const float4*)&Us[i][tx*8+4];
    float uv[8] = {u0.x,u0.y,u0.z,u0.w,u1.x,u1.y,u1.z,u1.w};
#pragma unroll
    for (int l=0;l<8;l++){
      acc[0][l] += sv0*uv[l];
      acc[1][l] += sv1*uv[l];
      acc[2][l] += sv2*uv[l];
      acc[3][l] += sv3*uv[l];
    }
  }

  // main GEMM: chunk @ M0^T
  const float* xc = x + ((size_t)b*SEQ + (size_t)j*64)*DIN;
  int at = tid>>2, adq = tid&3;
  int bol = tid&127, bhalf = tid>>7;
  for (int d0=0; d0<DIN; d0+=16){
    float4 v  = *(const float4*)(xc + (size_t)at*DIN + d0 + adq*4);
    float4 m0 = *(const float4*)(M0 + (size_t)(O0+bol)*DIN + d0 + bhalf*8);
    float4 m1 = *(const float4*)(M0 + (size_t)(O0+bol)*DIN + d0 + bhalf*8+4);
    __syncthreads();
    As[adq*4+0][at]=v.x; As[adq*4+1][at]=v.y; As[adq*4+2][at]=v.z; As[adq*4+3][at]=v.w;
    Bs[bhalf*8+0][bol]=m0.x; Bs[bhalf*8+1][bol]=m0.y; Bs[bhalf*8+2][bol]=m0.z; Bs[bhalf*8+3][bol]=m0.w;
    Bs[bhalf*8+4][bol]=m1.x; Bs[bhalf*8+5][bol]=m1.y; Bs[bhalf*8+6][bol]=m1.z; Bs[bhalf*8+7][bol]=m1.w;
    __syncthreads();
#pragma unroll
    for (int dd=0; dd<16; dd++){
      float a0=As[dd][ty], a1=As[dd][ty+16], a2=As[dd][ty+32], a3=As[dd][ty+48];
      float4 b0 = *(const float4*)&Bs[dd][tx*8];
      float4 b1 = *(const float4*)&Bs[dd][tx*8+4];
      float bv[8]={b0.x,b0.y,b0.z,b0.w,b1.x,b1.y,b1.z,b1.w};
#pragma unroll
      for (int l=0;l<8;l++){
        acc[0][l] += a0*bv[l];
        acc[1][l] += a1*bv[l];
        acc[2][l] += a2*bv[l];
        acc[3][l] += a3*bv[l];
      }
    }
  }

  float p = P[b*(NCH+1)+j];
#pragma unroll
  for (int k=0;k<4;k++){
    float4 o0, o1;
    o0.x=p*acc[k][0]; o0.y=p*acc[k][1]; o0.z=p*acc[k][2]; o0.w=p*acc[k][3];
    o1.x=p*acc[k][4]; o1.y=p*acc[k][5]; o1.z=p*acc[k][6]; o1.w=p*acc[k][7];
    float* orow = out + ((size_t)b*SEQ + (size_t)j*64 + ty+16*k)*DOUT + O0 + tx*8;
    *(float4*)orow     = o0;
    *(float4*)(orow+4) = o1;
  }
}

// ---------------- K5: M_fin = p64*(M0 + sum_i r_i u_i km_i^T) ----------------
__global__ __launch_bounds__(256) void k5_mfin(
    const float* __restrict__ M0, const float* __restrict__ KM,
    const float* __restrict__ U, const float* __restrict__ P, const float* __restrict__ R,
    float* __restrict__ Mout)
{
  int ob = blockIdx.x, b = blockIdx.y;   // ob: 64 blocks x 8 rows
  int tid = threadIdx.x;
  __shared__ float uo[64][8];
  for (int idx=tid; idx<512; idx+=256){
    int i = idx>>3, oo = idx&7;
    uo[i][oo] = R[b*NCH+i] * U[((size_t)b*NCH+i)*DOUT + ob*8+oo];
  }
  __syncthreads();
  float p64 = P[b*(NCH+1)+NCH];
  float acc[2][8];
#pragma unroll
  for (int h=0;h<2;h++)
#pragma unroll
    for (int oo=0;oo<8;oo++) acc[h][oo]=0.f;
  int d0 = tid, d1 = tid+256;
  for (int i=0;i<64;i++){
    float k0 = KM[((size_t)b*NCH+i)*DIN + d0];
    float k1 = KM[((size_t)b*NCH+i)*DIN + d1];
#pragma unroll
    for (int oo=0;oo<8;oo++){
      float u = uo[i][oo];
      acc[0][oo] += u*k0;
      acc[1][oo] += u*k1;
    }
  }
#pragma unroll
  for (int oo=0;oo<8;oo++){
    int o = ob*8+oo;
    Mout[((size_t)b*DOUT + o)*DIN + d0] = p64*(M0[(size_t)o*DIN+d0] + acc[0][oo]);
    Mout[((size_t)b*DOUT + o)*DIN + d1] = p64*(M0[(size_t)o*DIN+d1] + acc[1][oo]);
  }
}

// ---------------- launch ----------------
extern "C" void kernel_launch(void* const* d_in, const int* in_sizes, int n_in,
                              void* d_out, int out_size, void* d_ws, size_t ws_size,
                              hipStream_t stream) {
  const float* x       = (const float*)d_in[0];
  const float* M0      = (const float*)d_in[1];
  const float* eta_w   = (const float*)d_in[2];
  const float* eta_b   = (const float*)d_in[3];
  const float* alpha_w = (const float*)d_in[4];
  const float* alpha_b = (const float*)d_in[5];
  const float* gate_w  = (const float*)d_in[6];
  const float* gate_b  = (const float*)d_in[7];
  float* out = (float*)d_out;

  float* ws = (float*)d_ws;
  // workspace layout (floats)
  float* KM   = ws;                       // 8*64*512
  float* Dv   = KM   + 262144;            // 8*64*512
  float* G0   = Dv   + 262144;            // 8*64*512
  float* H0   = G0   + 262144;            // 8*64*512
  float* U    = H0   + 262144;            // 8*64*512
  float* S    = U    + 262144;            // 8*4096*64
  float* KMD  = S    + 2097152;           // 8*64*64
  float* KMKM = KMD  + 32768;             // 8*64*64
  float* C1   = KMKM + 32768;             // 8*64
  float* C2   = C1   + 512;               // 8*64
  float* KM2  = C2   + 512;               // 8*64
  float* P    = KM2  + 512;               // 8*65
  float* R    = P    + 520;               // 8*64

  k1_stats<<<dim3(NCH, NB), 256, 0, stream>>>(x, eta_w, eta_b, alpha_w, alpha_b,
                                              gate_w, gate_b, KM, Dv, C1, C2, KM2);
  k2_g0h0<<<dim3(NCH, NB), 256, 0, stream>>>(KM, Dv, M0, G0, H0);
  k2b_gram<<<dim3(NCH, NB), 256, 0, stream>>>(KM, Dv, KMD, KMKM);
  k3_scan<<<dim3(NB), 512, 0, stream>>>(M0, G0, H0, KMD, KMKM, C1, C2, KM2, U, P, R);
  k4s_s<<<dim3(SEQ/64, NB), 256, 0, stream>>>(x, KM, S);
  k4_out<<<dim3(4, NCH, NB), 256, 0, stream>>>(x, M0, S, U, P, R, out);
  k5_mfin<<<dim3(64, NB), 256, 0, stream>>>(M0, KM, U, P, R, out + (size_t)NB*SEQ*DOUT);
}

// Round 3
// 527.914 us; speedup vs baseline: 1.3350x; 1.3350x over previous
//
#include <hip/hip_runtime.h>
#include <math.h>

#define DIN  512
#define DOUT 512
#define CHK  64
#define NCH  64
#define NB   8
#define SEQ  4096

typedef short bh8_t __attribute__((ext_vector_type(8)));
typedef float f32x4 __attribute__((ext_vector_type(4)));

__device__ __forceinline__ float sigmoidf_(float z){ return 1.0f/(1.0f+__expf(-z)); }

__device__ __forceinline__ unsigned short f2bf(float f){
  unsigned u = __float_as_uint(f);
  unsigned r = (u + 0x7fffu + ((u>>16)&1u)) >> 16;
  return (unsigned short)r;
}
__device__ __forceinline__ void store_bf4(unsigned short* p, float4 v){
  uint2 u;
  u.x = (unsigned)f2bf(v.x) | ((unsigned)f2bf(v.y)<<16);
  u.y = (unsigned)f2bf(v.z) | ((unsigned)f2bf(v.w)<<16);
  *(uint2*)p = u;
}

// ---------------- K0: M0 -> bf16 copy ----------------
__global__ __launch_bounds__(256) void k0_m0h(const float* __restrict__ M0, unsigned short* __restrict__ M0h){
  int idx = (blockIdx.x*256 + threadIdx.x)*4;
  float4 v = *(const float4*)(M0+idx);
  store_bf4(M0h+idx, v);
}

// ---------------- K1: per-(batch,chunk) statistics ----------------
__global__ __launch_bounds__(256) void k1_stats(
    const float* __restrict__ x,
    const float* __restrict__ eta_w, const float* __restrict__ eta_b,
    const float* __restrict__ alpha_w, const float* __restrict__ alpha_b,
    const float* __restrict__ gate_w, const float* __restrict__ gate_b,
    float* __restrict__ KM, float* __restrict__ Dv, unsigned short* __restrict__ KMh,
    float* __restrict__ C1, float* __restrict__ C2, float* __restrict__ KM2, float* __restrict__ Q)
{
  int j = blockIdx.x, b = blockIdx.y;
  const float* xc = x + ((size_t)b*SEQ + (size_t)j*CHK) * DIN;
  int tid = threadIdx.x;
  int wave = tid >> 6, lane = tid & 63;

  float km_acc[8], xb_acc[8];
#pragma unroll
  for (int k=0;k<8;k++){ km_acc[k]=0.f; xb_acc[k]=0.f; }
  float eta_sum = 0.f, alpha_sum = 0.f;
  float ew[8], aw[8];
#pragma unroll
  for (int k=0;k<8;k++){ ew[k]=eta_w[lane*8+k]; aw[k]=alpha_w[lane*8+k]; }

  for (int tt=0; tt<16; tt++){
    int t = wave*16 + tt;
    const float* xr = xc + (size_t)t*DIN + lane*8;
    float v[8];
#pragma unroll
    for (int k=0;k<8;k++) v[k]=xr[k];
    float pe=0.f, pa=0.f, pn=0.f;
#pragma unroll
    for (int k=0;k<8;k++){ pe += v[k]*ew[k]; pa += v[k]*aw[k]; pn += v[k]*v[k]; }
#pragma unroll
    for (int off=32; off; off>>=1){
      pe += __shfl_xor(pe, off);
      pa += __shfl_xor(pa, off);
      pn += __shfl_xor(pn, off);
    }
    float inv = 1.0f / fmaxf(sqrtf(pn), 1e-5f);
    eta_sum   += sigmoidf_(pe + eta_b[0]);
    alpha_sum += sigmoidf_(pa + alpha_b[0]);
#pragma unroll
    for (int k=0;k<8;k++){ km_acc[k] += v[k]*inv; xb_acc[k] += v[k]; }
  }

  __shared__ float sKM[4][DIN];
  __shared__ float sXB[4][DIN];
  __shared__ float sEA[4][2];
  __shared__ float sred[4][2];
#pragma unroll
  for (int k=0;k<8;k++){ sKM[wave][lane*8+k]=km_acc[k]; sXB[wave][lane*8+k]=xb_acc[k]; }
  if (lane==0){ sEA[wave][0]=eta_sum; sEA[wave][1]=alpha_sum; }
  __syncthreads();

  float gpart=0.f, km2part=0.f;
  float kmv[2], dvv[2];
#pragma unroll
  for (int k=0;k<2;k++){
    int d = tid*2+k;
    float km = (sKM[0][d]+sKM[1][d]+sKM[2][d]+sKM[3][d]) * (1.0f/64.0f);
    float xb = (sXB[0][d]+sXB[1][d]+sXB[2][d]+sXB[3][d]) * (1.0f/64.0f);
    kmv[k]=km; dvv[k]=xb-km;
    gpart  += km * gate_w[d];
    km2part+= km * km;
  }
#pragma unroll
  for (int off=32; off; off>>=1){
    gpart   += __shfl_xor(gpart, off);
    km2part += __shfl_xor(km2part, off);
  }
  if (lane==0){ sred[wave][0]=gpart; sred[wave][1]=km2part; }
  __syncthreads();

  size_t base = ((size_t)b*NCH + j)*DIN;
#pragma unroll
  for (int k=0;k<2;k++){
    int d = tid*2+k;
    KM[base+d]=kmv[k];
    Dv[base+d]=dvv[k];
    KMh[base+d]=f2bf(kmv[k]);
  }
  if (tid==0){
    float gdot = sred[0][0]+sred[1][0]+sred[2][0]+sred[3][0];
    float km2  = sred[0][1]+sred[1][1]+sred[2][1]+sred[3][1];
    float etam = (sEA[0][0]+sEA[1][0]+sEA[2][0]+sEA[3][0]) * (1.0f/64.0f);
    float alpm = (sEA[0][1]+sEA[1][1]+sEA[2][1]+sEA[3][1]) * (1.0f/64.0f);
    float eta   = 0.2f * etam;
    float alpha = 0.5f + 0.5f * alpm;
    float gate  = sigmoidf_(gdot + gate_b[0]);
    float c1 = gate*alpha + 1.0f - gate;
    float c2 = gate*eta;
    C1[b*NCH+j]  = c1;
    C2[b*NCH+j]  = c2;
    KM2[b*NCH+j] = km2;
    Q[b*NCH+j]   = c2/c1;
  }
}

// ---------------- K2: G0 = D @ M0^T, H0 = KM @ M0^T (per b,j) ----------------
__global__ __launch_bounds__(256) void k2_g0h0(
    const float* __restrict__ KM, const float* __restrict__ Dv,
    const float* __restrict__ M0, float* __restrict__ G0, float* __restrict__ H0)
{
  int j = blockIdx.x, b = blockIdx.y;
  __shared__ float sD[DIN], sK[DIN];
  int tid = threadIdx.x;
  size_t base = ((size_t)b*NCH+j)*DIN;
  for (int d=tid; d<DIN; d+=256){ sD[d]=Dv[base+d]; sK[d]=KM[base+d]; }
  __syncthreads();
  for (int o=tid; o<DOUT; o+=256){
    const float* mr = M0 + (size_t)o*DIN;
    float ag=0.f, ah=0.f;
    for (int d=0; d<DIN; d+=4){
      float4 m = *(const float4*)(mr+d);
      ag += m.x*sD[d] + m.y*sD[d+1] + m.z*sD[d+2] + m.w*sD[d+3];
      ah += m.x*sK[d] + m.y*sK[d+1] + m.z*sK[d+2] + m.w*sK[d+3];
    }
    G0[base+o]=ag; H0[base+o]=ah;
  }
}

// ---------------- K2b: Gram matrices ----------------
__global__ __launch_bounds__(256) void k2b_gram(
    const float* __restrict__ KM, const float* __restrict__ Dv,
    float* __restrict__ KMD, float* __restrict__ KMKM)
{
  int i = blockIdx.x, b = blockIdx.y;
  __shared__ float sKi[DIN];
  int tid = threadIdx.x;
  const float* kmi = KM + ((size_t)b*NCH+i)*DIN;
  for (int d=tid; d<DIN; d+=256) sKi[d]=kmi[d];
  __syncthreads();
  int wave = tid>>6, lane = tid&63;
  for (int j=wave; j<NCH; j+=4){
    const float* dj = Dv + ((size_t)b*NCH+j)*DIN;
    const float* kj = KM + ((size_t)b*NCH+j)*DIN;
    float pd=0.f, pk=0.f;
#pragma unroll
    for (int k=0;k<8;k++){
      int d = lane + k*64;
      pd += sKi[d]*dj[d];
      pk += sKi[d]*kj[d];
    }
#pragma unroll
    for (int off=32; off; off>>=1){ pd += __shfl_xor(pd,off); pk += __shfl_xor(pk,off); }
    if (lane==0){
      KMD [((size_t)b*NCH+i)*NCH + j] = pd;
      KMKM[((size_t)b*NCH+i)*NCH + j] = pk;
    }
  }
}

// ---------------- K3a: barrier-free triangular recurrence (AU, AW) ----------------
__global__ __launch_bounds__(512) void k3a_au(
    const float* __restrict__ G0, const float* __restrict__ H0,
    const float* __restrict__ KMD, const float* __restrict__ KMKM,
    const float* __restrict__ Q, float* __restrict__ AU, float* __restrict__ AW)
{
  int b = blockIdx.x, tid = threadIdx.x;
  __shared__ float scM[4096], scW[4096];
  for (int idx=tid; idx<4096; idx+=512){
    int i=idx>>6, jj=idx&63;
    float qv = Q[b*NCH+i];
    scM[idx] = qv*KMD [((size_t)b*NCH+i)*NCH+jj];
    scW[idx] = qv*KMKM[((size_t)b*NCH+i)*NCH+jj];
  }
  __syncthreads();
  float au[NCH];
  size_t gb = (size_t)b*NCH*DIN + tid;
#pragma unroll 64
  for (int j=0;j<NCH;j++){
    float a = G0[gb + (size_t)j*DIN];
    float w = H0[gb + (size_t)j*DIN];
#pragma unroll
    for (int i=0;i<j;i++){
      a += scM[i*64+j]*au[i];
      w += scW[i*64+j]*au[i];
    }
    au[j]=a;
    AU[gb + (size_t)j*DIN] = a;
    AW[gb + (size_t)j*DIN] = w;
  }
}

// ---------------- K3b: dots ----------------
__global__ __launch_bounds__(256) void k3b_dots(
    const float* __restrict__ AU, const float* __restrict__ AW,
    float* __restrict__ DUW, float* __restrict__ DUU)
{
  int j = blockIdx.x, b = blockIdx.y;
  int tid = threadIdx.x, wave = tid>>6, lane = tid&63;
  size_t base = ((size_t)b*NCH + j)*DIN;
  float s1=0.f, s2=0.f;
  for (int o=tid; o<DIN; o+=256){
    float u = AU[base+o], w = AW[base+o];
    s1 += u*w; s2 += u*u;
  }
#pragma unroll
  for (int off=32; off; off>>=1){ s1+=__shfl_xor(s1,off); s2+=__shfl_xor(s2,off); }
  __shared__ float r1[4], r2[4];
  if (lane==0){ r1[wave]=s1; r2[wave]=s2; }
  __syncthreads();
  if (tid==0){
    DUW[b*NCH+j] = r1[0]+r1[1]+r1[2]+r1[3];
    DUU[b*NCH+j] = r2[0]+r2[1]+r2[2]+r2[3];
  }
}

// ---------------- K3c: scalar p-chain ----------------
__global__ __launch_bounds__(256) void k3c_chain(
    const float* __restrict__ M0,
    const float* __restrict__ C1, const float* __restrict__ C2, const float* __restrict__ KM2,
    const float* __restrict__ DUW, const float* __restrict__ DUU, float* __restrict__ P)
{
  int b = blockIdx.x, tid = threadIdx.x, wave = tid>>6, lane = tid&63;
  float f=0.f;
  const float4* m4 = (const float4*)M0;
  for (int i=tid; i<(DOUT*DIN)/4; i+=256){
    float4 v=m4[i];
    f += v.x*v.x + v.y*v.y + v.z*v.z + v.w*v.w;
  }
#pragma unroll
  for (int off=32; off; off>>=1) f += __shfl_xor(f,off);
  __shared__ float rf[4];
  if (lane==0) rf[wave]=f;
  __syncthreads();
  if (tid==0){
    float F = rf[0]+rf[1]+rf[2]+rf[3];
    float p = 1.f;
    P[b*65+0] = 1.f;
    for (int j=0;j<NCH;j++){
      float c1 = C1[b*NCH+j], c2 = C2[b*NCH+j], km2 = KM2[b*NCH+j];
      float uw = p*p*DUW[b*NCH+j];
      float uu = p*p*DUU[b*NCH+j];
      float Fnew = c1*c1*F + 2.f*c1*c2*uw + c2*c2*uu*km2;
      float scale = fminf(30.0f/(sqrtf(Fnew)+1e-6f), 1.0f);
      F = scale*scale*Fnew;
      p = scale*c1*p;
      P[b*65+j+1] = p;
    }
  }
}

// ---------------- K3d: UQT[o][i] = bf16(q_i * AU[i][o]) ----------------
__global__ __launch_bounds__(256) void k3d_uqt(
    const float* __restrict__ AU, const float* __restrict__ Q, unsigned short* __restrict__ UQTh)
{
  int og = blockIdx.x, b = blockIdx.y;
  int tid = threadIdx.x;
  for (int it=0; it<16; it++){
    int idx = it*256 + tid;
    int o = og*64 + (idx>>6);
    int i = idx & 63;
    float v = Q[b*NCH+i] * AU[((size_t)b*NCH+i)*DIN + o];
    UQTh[((size_t)b*DOUT + o)*NCH + i] = f2bf(v);
  }
}

// ---------------- K4s: Sh = bf16( X @ KM^T ), MFMA ----------------
__global__ __launch_bounds__(256) void k4s_s(
    const float* __restrict__ x, const unsigned short* __restrict__ KMh,
    unsigned short* __restrict__ Sh)
{
  int tt = blockIdx.x, b = blockIdx.y;
  int tid = threadIdx.x;
  int lane = tid&63, w = tid>>6, m = lane&15, q = lane>>4;
  __shared__ unsigned short As[64*72];
  __shared__ unsigned short Bs[64*72];
  f32x4 acc[4];
  f32x4 z = {0.f,0.f,0.f,0.f};
#pragma unroll
  for (int nf=0;nf<4;nf++) acc[nf]=z;

  const float* xc = x + ((size_t)b*SEQ + (size_t)tt*64)*DIN;
  for (int k0=0;k0<DIN;k0+=64){
    float4 xa[4]; uint4 bb[2];
#pragma unroll
    for (int v=0;v<4;v++){
      int idx=v*256+tid; int row=idx>>4, cc=idx&15;
      xa[v] = *(const float4*)(xc + (size_t)row*DIN + k0 + cc*4);
    }
    // KMh tile: 64 rows x 64 shorts = 512 uint4 loads (8 shorts each)
#pragma unroll
    for (int v=0;v<2;v++){
      int idx=v*256+tid; int il=idx>>3, cc=idx&7;
      bb[v] = *(const uint4*)&KMh[((size_t)b*NCH+il)*DIN + k0 + cc*8];
    }
    __syncthreads();
#pragma unroll
    for (int v=0;v<4;v++){
      int idx=v*256+tid; int row=idx>>4, cc=idx&15;
      store_bf4(&As[row*72 + cc*4], xa[v]);
    }
#pragma unroll
    for (int v=0;v<2;v++){
      int idx=v*256+tid; int il=idx>>3, cc=idx&7;
      *(uint4*)&Bs[il*72 + cc*8] = bb[v];
    }
    __syncthreads();
#pragma unroll
    for (int kk=0;kk<2;kk++){
      bh8_t af = *(bh8_t*)&As[(w*16+m)*72 + kk*32 + q*8];
#pragma unroll
      for (int nf=0;nf<4;nf++){
        bh8_t bf_ = *(bh8_t*)&Bs[(nf*16+m)*72 + kk*32 + q*8];
        acc[nf] = __builtin_amdgcn_mfma_f32_16x16x32_bf16(af, bf_, acc[nf], 0,0,0);
      }
    }
  }
#pragma unroll
  for (int nf=0;nf<4;nf++)
#pragma unroll
    for (int r=0;r<4;r++)
      Sh[((size_t)b*SEQ + (size_t)tt*64 + w*16 + q*4 + r)*NCH + nf*16 + m] = f2bf(acc[nf][r]);
}

// ---------------- K4: out = p_j*( Sc(masked)@UQT-slice + Xc@M0h^T ), MFMA ----------------
__global__ __launch_bounds__(256) void k4_out(
    const float* __restrict__ x, const unsigned short* __restrict__ M0h,
    const unsigned short* __restrict__ Sh, const unsigned short* __restrict__ UQTh,
    const float* __restrict__ P, float* __restrict__ out)
{
  int ot = blockIdx.x, j = blockIdx.y, b = blockIdx.z;
  int tid = threadIdx.x;
  int lane = tid&63, w = tid>>6, m = lane&15, q = lane>>4;
  int O0 = ot*128;
  __shared__ unsigned short lds[64*72 + 128*72];
  unsigned short* As = lds;
  unsigned short* Bs = lds + 64*72;
  f32x4 acc[8];
  f32x4 z = {0.f,0.f,0.f,0.f};
#pragma unroll
  for (int nf=0;nf<8;nf++) acc[nf]=z;

  // stage masked S tile (i<j) into As; UQT slice (128 rows x 64 shorts) into Bs
  for (int idx=tid; idx<64*64; idx+=256){
    int t = idx>>6, i = idx&63;
    unsigned short v = (i<j) ? Sh[((size_t)b*SEQ + (size_t)j*64 + t)*NCH + i] : (unsigned short)0;
    As[t*72+i] = v;
  }
#pragma unroll
  for (int v=0; v<4; v++){
    int idx = v*256+tid;
    int ol = idx>>3, cc = idx&7;
    *(uint4*)&Bs[ol*72 + cc*8] = *(const uint4*)&UQTh[((size_t)b*DOUT + O0+ol)*NCH + cc*8];
  }
  __syncthreads();
  // correction MFMAs (K=64 over i)
#pragma unroll
  for (int kk=0;kk<2;kk++){
    bh8_t af = *(bh8_t*)&As[(w*16+m)*72 + kk*32 + q*8];
#pragma unroll
    for (int nf=0;nf<8;nf++){
      bh8_t bf_ = *(bh8_t*)&Bs[(nf*16+m)*72 + kk*32 + q*8];
      acc[nf] = __builtin_amdgcn_mfma_f32_16x16x32_bf16(af, bf_, acc[nf], 0,0,0);
    }
  }

  // main GEMM: Xc @ M0h^T
  const float* xc = x + ((size_t)b*SEQ + (size_t)j*64)*DIN;
  for (int k0=0;k0<DIN;k0+=64){
    float4 xa[4]; uint4 bb[4];
#pragma unroll
    for (int v=0;v<4;v++){
      int idx=v*256+tid; int row=idx>>4, cc=idx&15;
      xa[v] = *(const float4*)(xc + (size_t)row*DIN + k0 + cc*4);
    }
    // M0h tile: 128 rows x 64 shorts = 1024 uint4 loads
#pragma unroll
    for (int v=0;v<4;v++){
      int idx=v*256+tid; int ol=idx>>3, cc=idx&7;
      bb[v] = *(const uint4*)&M0h[(size_t)(O0+ol)*DIN + k0 + cc*8];
    }
    __syncthreads();
#pragma unroll
    for (int v=0;v<4;v++){
      int idx=v*256+tid; int row=idx>>4, cc=idx&15;
      store_bf4(&As[row*72 + cc*4], xa[v]);
    }
#pragma unroll
    for (int v=0;v<4;v++){
      int idx=v*256+tid; int ol=idx>>3, cc=idx&7;
      *(uint4*)&Bs[ol*72 + cc*8] = bb[v];
    }
    __syncthreads();
#pragma unroll
    for (int kk=0;kk<2;kk++){
      bh8_t af = *(bh8_t*)&As[(w*16+m)*72 + kk*32 + q*8];
#pragma unroll
      for (int nf=0;nf<8;nf++){
        bh8_t bf_ = *(bh8_t*)&Bs[(nf*16+m)*72 + kk*32 + q*8];
        acc[nf] = __builtin_amdgcn_mfma_f32_16x16x32_bf16(af, bf_, acc[nf], 0,0,0);
      }
    }
  }

  float p = P[b*65 + j];
#pragma unroll
  for (int nf=0;nf<8;nf++)
#pragma unroll
    for (int r=0;r<4;r++)
      out[((size_t)b*SEQ + (size_t)j*64 + w*16 + q*4 + r)*DOUT + O0 + nf*16 + m] = p*acc[nf][r];
}

// ---------------- K5: M_fin = p64*(M0 + sum_i q_i AU_i km_i^T) ----------------
__global__ __launch_bounds__(256) void k5_mfin(
    const float* __restrict__ M0, const float* __restrict__ KM,
    const float* __restrict__ AU, const float* __restrict__ P, const float* __restrict__ Q,
    float* __restrict__ Mout)
{
  int ob = blockIdx.x, b = blockIdx.y;
  int tid = threadIdx.x;
  __shared__ float uo[64][8];
  for (int idx=tid; idx<512; idx+=256){
    int i = idx>>3, oo = idx&7;
    uo[i][oo] = Q[b*NCH+i] * AU[((size_t)b*NCH+i)*DOUT + ob*8+oo];
  }
  __syncthreads();
  float p64 = P[b*65+NCH];
  float acc[2][8];
#pragma unroll
  for (int h=0;h<2;h++)
#pragma unroll
    for (int oo=0;oo<8;oo++) acc[h][oo]=0.f;
  int d0 = tid, d1 = tid+256;
  for (int i=0;i<64;i++){
    float k0 = KM[((size_t)b*NCH+i)*DIN + d0];
    float k1 = KM[((size_t)b*NCH+i)*DIN + d1];
#pragma unroll
    for (int oo=0;oo<8;oo++){
      float u = uo[i][oo];
      acc[0][oo] += u*k0;
      acc[1][oo] += u*k1;
    }
  }
#pragma unroll
  for (int oo=0;oo<8;oo++){
    int o = ob*8+oo;
    Mout[((size_t)b*DOUT + o)*DIN + d0] = p64*(M0[(size_t)o*DIN+d0] + acc[0][oo]);
    Mout[((size_t)b*DOUT + o)*DIN + d1] = p64*(M0[(size_t)o*DIN+d1] + acc[1][oo]);
  }
}

// ---------------- launch ----------------
extern "C" void kernel_launch(void* const* d_in, const int* in_sizes, int n_in,
                              void* d_out, int out_size, void* d_ws, size_t ws_size,
                              hipStream_t stream) {
  const float* x       = (const float*)d_in[0];
  const float* M0      = (const float*)d_in[1];
  const float* eta_w   = (const float*)d_in[2];
  const float* eta_b   = (const float*)d_in[3];
  const float* alpha_w = (const float*)d_in[4];
  const float* alpha_b = (const float*)d_in[5];
  const float* gate_w  = (const float*)d_in[6];
  const float* gate_b  = (const float*)d_in[7];
  float* out = (float*)d_out;

  float* ws = (float*)d_ws;
  float* KM   = ws;                    // 262144
  float* Dv   = KM   + 262144;
  float* G0   = Dv   + 262144;
  float* H0   = G0   + 262144;
  float* AU   = H0   + 262144;
  float* AW   = AU   + 262144;
  float* KMD  = AW   + 262144;         // 32768
  float* KMKM = KMD  + 32768;          // 32768
  float* C1   = KMKM + 32768;          // 512
  float* C2   = C1   + 512;
  float* KM2  = C2   + 512;
  float* Q    = KM2  + 512;
  float* DUW  = Q    + 512;
  float* DUU  = DUW  + 512;
  float* P    = DUU  + 512;            // 1024 (8*65 used)
  unsigned short* M0h  = (unsigned short*)(P + 1024);      // 262144 shorts
  unsigned short* KMh  = M0h  + 262144;                    // 262144
  unsigned short* Sh   = KMh  + 262144;                    // 2097152
  unsigned short* UQTh = Sh   + 2097152;                   // 262144

  k0_m0h<<<dim3(256), 256, 0, stream>>>(M0, M0h);
  k1_stats<<<dim3(NCH, NB), 256, 0, stream>>>(x, eta_w, eta_b, alpha_w, alpha_b,
                                              gate_w, gate_b, KM, Dv, KMh, C1, C2, KM2, Q);
  k2_g0h0<<<dim3(NCH, NB), 256, 0, stream>>>(KM, Dv, M0, G0, H0);
  k2b_gram<<<dim3(NCH, NB), 256, 0, stream>>>(KM, Dv, KMD, KMKM);
  k4s_s<<<dim3(SEQ/64, NB), 256, 0, stream>>>(x, KMh, Sh);
  k3a_au<<<dim3(NB), 512, 0, stream>>>(G0, H0, KMD, KMKM, Q, AU, AW);
  k3b_dots<<<dim3(NCH, NB), 256, 0, stream>>>(AU, AW, DUW, DUU);
  k3c_chain<<<dim3(NB), 256, 0, stream>>>(M0, C1, C2, KM2, DUW, DUU, P);
  k3d_uqt<<<dim3(8, NB), 256, 0, stream>>>(AU, Q, UQTh);
  k4_out<<<dim3(4, NCH, NB), 256, 0, stream>>>(x, M0h, Sh, UQTh, P, out);
  k5_mfin<<<dim3(64, NB), 256, 0, stream>>>(M0, KM, AU, P, Q, out + (size_t)NB*SEQ*DOUT);
}

// Round 4
// 511.407 us; speedup vs baseline: 1.3781x; 1.0323x over previous
//
#include <hip/hip_runtime.h>
#include <math.h>

#define DIN  512
#define DOUT 512
#define CHK  64
#define NCH  64
#define NB   8
#define SEQ  4096

typedef short bh8_t __attribute__((ext_vector_type(8)));
typedef float f32x4 __attribute__((ext_vector_type(4)));

__device__ __forceinline__ float sigmoidf_(float z){ return 1.0f/(1.0f+__expf(-z)); }

__device__ __forceinline__ unsigned short f2bf(float f){
  unsigned u = __float_as_uint(f);
  unsigned r = (u + 0x7fffu + ((u>>16)&1u)) >> 16;
  return (unsigned short)r;
}
__device__ __forceinline__ void store_bf4(unsigned short* p, float4 v){
  uint2 u;
  u.x = (unsigned)f2bf(v.x) | ((unsigned)f2bf(v.y)<<16);
  u.y = (unsigned)f2bf(v.z) | ((unsigned)f2bf(v.w)<<16);
  *(uint2*)p = u;
}

// ---------------- K0: M0 -> bf16 ----------------
__global__ __launch_bounds__(256) void k0_m0h(const float* __restrict__ M0, unsigned short* __restrict__ M0h){
  int idx = (blockIdx.x*256 + threadIdx.x)*4;
  float4 v = *(const float4*)(M0+idx);
  store_bf4(M0h+idx, v);
}

// ---------------- K1: per-(batch,chunk) statistics (+ x -> bf16 when xh != null) ----------------
__global__ __launch_bounds__(256) void k1_stats(
    const float* __restrict__ x,
    const float* __restrict__ eta_w, const float* __restrict__ eta_b,
    const float* __restrict__ alpha_w, const float* __restrict__ alpha_b,
    const float* __restrict__ gate_w, const float* __restrict__ gate_b,
    float* __restrict__ KM, float* __restrict__ Dv, unsigned short* __restrict__ KMh,
    float* __restrict__ C1, float* __restrict__ C2, float* __restrict__ KM2, float* __restrict__ Q,
    unsigned short* __restrict__ xh)
{
  int j = blockIdx.x, b = blockIdx.y;
  const float* xc = x + ((size_t)b*SEQ + (size_t)j*CHK) * DIN;
  int tid = threadIdx.x;
  int wave = tid >> 6, lane = tid & 63;

  float km_acc[8], xb_acc[8];
#pragma unroll
  for (int k=0;k<8;k++){ km_acc[k]=0.f; xb_acc[k]=0.f; }
  float eta_sum = 0.f, alpha_sum = 0.f;
  float ew[8], aw[8];
#pragma unroll
  for (int k=0;k<8;k++){ ew[k]=eta_w[lane*8+k]; aw[k]=alpha_w[lane*8+k]; }

  for (int tt=0; tt<16; tt++){
    int t = wave*16 + tt;
    const float* xr = xc + (size_t)t*DIN + lane*8;
    float v[8];
#pragma unroll
    for (int k=0;k<8;k++) v[k]=xr[k];
    if (xh){
      uint4 hv;
      hv.x = (unsigned)f2bf(v[0]) | ((unsigned)f2bf(v[1])<<16);
      hv.y = (unsigned)f2bf(v[2]) | ((unsigned)f2bf(v[3])<<16);
      hv.z = (unsigned)f2bf(v[4]) | ((unsigned)f2bf(v[5])<<16);
      hv.w = (unsigned)f2bf(v[6]) | ((unsigned)f2bf(v[7])<<16);
      *(uint4*)&xh[((size_t)b*SEQ + (size_t)j*CHK + t)*DIN + lane*8] = hv;
    }
    float pe=0.f, pa=0.f, pn=0.f;
#pragma unroll
    for (int k=0;k<8;k++){ pe += v[k]*ew[k]; pa += v[k]*aw[k]; pn += v[k]*v[k]; }
#pragma unroll
    for (int off=32; off; off>>=1){
      pe += __shfl_xor(pe, off);
      pa += __shfl_xor(pa, off);
      pn += __shfl_xor(pn, off);
    }
    float inv = 1.0f / fmaxf(sqrtf(pn), 1e-5f);
    eta_sum   += sigmoidf_(pe + eta_b[0]);
    alpha_sum += sigmoidf_(pa + alpha_b[0]);
#pragma unroll
    for (int k=0;k<8;k++){ km_acc[k] += v[k]*inv; xb_acc[k] += v[k]; }
  }

  __shared__ float sKM[4][DIN];
  __shared__ float sXB[4][DIN];
  __shared__ float sEA[4][2];
  __shared__ float sred[4][2];
#pragma unroll
  for (int k=0;k<8;k++){ sKM[wave][lane*8+k]=km_acc[k]; sXB[wave][lane*8+k]=xb_acc[k]; }
  if (lane==0){ sEA[wave][0]=eta_sum; sEA[wave][1]=alpha_sum; }
  __syncthreads();

  float gpart=0.f, km2part=0.f;
  float kmv[2], dvv[2];
#pragma unroll
  for (int k=0;k<2;k++){
    int d = tid*2+k;
    float km = (sKM[0][d]+sKM[1][d]+sKM[2][d]+sKM[3][d]) * (1.0f/64.0f);
    float xb = (sXB[0][d]+sXB[1][d]+sXB[2][d]+sXB[3][d]) * (1.0f/64.0f);
    kmv[k]=km; dvv[k]=xb-km;
    gpart  += km * gate_w[d];
    km2part+= km * km;
  }
#pragma unroll
  for (int off=32; off; off>>=1){
    gpart   += __shfl_xor(gpart, off);
    km2part += __shfl_xor(km2part, off);
  }
  if (lane==0){ sred[wave][0]=gpart; sred[wave][1]=km2part; }
  __syncthreads();

  size_t base = ((size_t)b*NCH + j)*DIN;
#pragma unroll
  for (int k=0;k<2;k++){
    int d = tid*2+k;
    KM[base+d]=kmv[k];
    Dv[base+d]=dvv[k];
    KMh[base+d]=f2bf(kmv[k]);
  }
  if (tid==0){
    float gdot = sred[0][0]+sred[1][0]+sred[2][0]+sred[3][0];
    float km2  = sred[0][1]+sred[1][1]+sred[2][1]+sred[3][1];
    float etam = (sEA[0][0]+sEA[1][0]+sEA[2][0]+sEA[3][0]) * (1.0f/64.0f);
    float alpm = (sEA[0][1]+sEA[1][1]+sEA[2][1]+sEA[3][1]) * (1.0f/64.0f);
    float eta   = 0.2f * etam;
    float alpha = 0.5f + 0.5f * alpm;
    float gate  = sigmoidf_(gdot + gate_b[0]);
    float c1 = gate*alpha + 1.0f - gate;
    float c2 = gate*eta;
    C1[b*NCH+j]  = c1;
    C2[b*NCH+j]  = c2;
    KM2[b*NCH+j] = km2;
    Q[b*NCH+j]   = c2/c1;
  }
}

// ---------------- K2: G0 = D @ M0^T, H0 = KM @ M0^T ----------------
__global__ __launch_bounds__(256) void k2_g0h0(
    const float* __restrict__ KM, const float* __restrict__ Dv,
    const float* __restrict__ M0, float* __restrict__ G0, float* __restrict__ H0)
{
  int j = blockIdx.x, b = blockIdx.y;
  __shared__ float sD[DIN], sK[DIN];
  int tid = threadIdx.x;
  size_t base = ((size_t)b*NCH+j)*DIN;
  for (int d=tid; d<DIN; d+=256){ sD[d]=Dv[base+d]; sK[d]=KM[base+d]; }
  __syncthreads();
  for (int o=tid; o<DOUT; o+=256){
    const float* mr = M0 + (size_t)o*DIN;
    float ag=0.f, ah=0.f;
    for (int d=0; d<DIN; d+=4){
      float4 m = *(const float4*)(mr+d);
      ag += m.x*sD[d] + m.y*sD[d+1] + m.z*sD[d+2] + m.w*sD[d+3];
      ah += m.x*sK[d] + m.y*sK[d+1] + m.z*sK[d+2] + m.w*sK[d+3];
    }
    G0[base+o]=ag; H0[base+o]=ah;
  }
}

// ---------------- K2b: Gram matrices ----------------
__global__ __launch_bounds__(256) void k2b_gram(
    const float* __restrict__ KM, const float* __restrict__ Dv,
    float* __restrict__ KMD, float* __restrict__ KMKM)
{
  int i = blockIdx.x, b = blockIdx.y;
  __shared__ float sKi[DIN];
  int tid = threadIdx.x;
  const float* kmi = KM + ((size_t)b*NCH+i)*DIN;
  for (int d=tid; d<DIN; d+=256) sKi[d]=kmi[d];
  __syncthreads();
  int wave = tid>>6, lane = tid&63;
  for (int j=wave; j<NCH; j+=4){
    const float* dj = Dv + ((size_t)b*NCH+j)*DIN;
    const float* kj = KM + ((size_t)b*NCH+j)*DIN;
    float pd=0.f, pk=0.f;
#pragma unroll
    for (int k=0;k<8;k++){
      int d = lane + k*64;
      pd += sKi[d]*dj[d];
      pk += sKi[d]*kj[d];
    }
#pragma unroll
    for (int off=32; off; off>>=1){ pd += __shfl_xor(pd,off); pk += __shfl_xor(pk,off); }
    if (lane==0){
      KMD [((size_t)b*NCH+i)*NCH + j] = pd;
      KMKM[((size_t)b*NCH+i)*NCH + j] = pk;
    }
  }
}

// ---------------- K3a: in-register triangular recurrence + dots + UQT pack ----------------
// grid (2, NB), 256 threads; d = half*256 + tid
__global__ __launch_bounds__(256) void k3a_au(
    const float* __restrict__ G0, const float* __restrict__ H0,
    const float* __restrict__ KMD, const float* __restrict__ KMKM,
    const float* __restrict__ Q, float* __restrict__ AU,
    unsigned short* __restrict__ UQTh,
    float* __restrict__ DUW, float* __restrict__ DUU)
{
  int half = blockIdx.x, b = blockIdx.y;
  int tid = threadIdx.x, wave = tid>>6, lane = tid&63;
  int d = half*256 + tid;
  __shared__ float scM[4096], scW[4096];
  __shared__ float sq[64];
  __shared__ float sdots[64][4][2];

  for (int idx=tid; idx<4096; idx+=256){
    int i=idx>>6, jj=idx&63;
    float qv = Q[b*NCH+i];
    scM[idx] = qv*KMD [((size_t)b*NCH+i)*NCH+jj];
    scW[idx] = qv*KMKM[((size_t)b*NCH+i)*NCH+jj];
  }
  if (tid<64) sq[tid] = Q[b*NCH+tid];
  __syncthreads();

  // preload all 64 G0 values (independent coalesced loads, pipelined)
  float au[NCH];
  size_t gb = (size_t)b*NCH*DOUT + d;
#pragma unroll
  for (int j=0;j<NCH;j++) au[j] = G0[gb + (size_t)j*DOUT];

  // phase 1: in-register recurrence
#pragma unroll
  for (int j=0;j<NCH;j++){
    float a = au[j];
#pragma unroll
    for (int i=0;i<j;i++) a += scM[i*64+j]*au[i];
    au[j]=a;
  }
  // AU out (for k5)
#pragma unroll
  for (int j=0;j<NCH;j++) AU[gb + (size_t)j*DOUT] = au[j];

  // UQT pack: row d, 64 bf16 (q_i * au_i)
#pragma unroll
  for (int g=0; g<8; g++){
    uint4 hv;
    hv.x = (unsigned)f2bf(au[g*8+0]*sq[g*8+0]) | ((unsigned)f2bf(au[g*8+1]*sq[g*8+1])<<16);
    hv.y = (unsigned)f2bf(au[g*8+2]*sq[g*8+2]) | ((unsigned)f2bf(au[g*8+3]*sq[g*8+3])<<16);
    hv.z = (unsigned)f2bf(au[g*8+4]*sq[g*8+4]) | ((unsigned)f2bf(au[g*8+5]*sq[g*8+5])<<16);
    hv.w = (unsigned)f2bf(au[g*8+6]*sq[g*8+6]) | ((unsigned)f2bf(au[g*8+7]*sq[g*8+7])<<16);
    *(uint4*)&UQTh[((size_t)b*DOUT + d)*NCH + g*8] = hv;
  }

  // phase 2: w_j + partial dots (H0 loads are off the critical path)
#pragma unroll
  for (int j=0;j<NCH;j++){
    float w = H0[gb + (size_t)j*DOUT];
#pragma unroll
    for (int i=0;i<j;i++) w += scW[i*64+j]*au[i];
    float s1 = au[j]*w, s2 = au[j]*au[j];
#pragma unroll
    for (int off=32; off; off>>=1){ s1+=__shfl_xor(s1,off); s2+=__shfl_xor(s2,off); }
    if (lane==0){ sdots[j][wave][0]=s1; sdots[j][wave][1]=s2; }
  }
  __syncthreads();
  if (tid<64){
    int j = tid;
    float uw = sdots[j][0][0]+sdots[j][1][0]+sdots[j][2][0]+sdots[j][3][0];
    float uu = sdots[j][0][1]+sdots[j][1][1]+sdots[j][2][1]+sdots[j][3][1];
    DUW[(b*NCH+j)*2 + half] = uw;
    DUU[(b*NCH+j)*2 + half] = uu;
  }
}

// ---------------- K3c: scalar p-chain ----------------
__global__ __launch_bounds__(256) void k3c_chain(
    const float* __restrict__ M0,
    const float* __restrict__ C1, const float* __restrict__ C2, const float* __restrict__ KM2,
    const float* __restrict__ DUW, const float* __restrict__ DUU, float* __restrict__ P)
{
  int b = blockIdx.x, tid = threadIdx.x, wave = tid>>6, lane = tid&63;
  float f=0.f;
  const float4* m4 = (const float4*)M0;
  for (int i=tid; i<(DOUT*DIN)/4; i+=256){
    float4 v=m4[i];
    f += v.x*v.x + v.y*v.y + v.z*v.z + v.w*v.w;
  }
#pragma unroll
  for (int off=32; off; off>>=1) f += __shfl_xor(f,off);
  __shared__ float rf[4];
  if (lane==0) rf[wave]=f;
  __syncthreads();
  if (tid==0){
    float F = rf[0]+rf[1]+rf[2]+rf[3];
    float p = 1.f;
    P[b*65+0] = 1.f;
    for (int j=0;j<NCH;j++){
      float c1 = C1[b*NCH+j], c2 = C2[b*NCH+j], km2 = KM2[b*NCH+j];
      float uw = p*p*(DUW[(b*NCH+j)*2]+DUW[(b*NCH+j)*2+1]);
      float uu = p*p*(DUU[(b*NCH+j)*2]+DUU[(b*NCH+j)*2+1]);
      float Fnew = c1*c1*F + 2.f*c1*c2*uw + c2*c2*uu*km2;
      float scale = fminf(30.0f/(sqrtf(Fnew)+1e-6f), 1.0f);
      F = scale*scale*Fnew;
      p = scale*c1*p;
      P[b*65+j+1] = p;
    }
  }
}

// ---------------- K4s: Sh = bf16( X @ KM^T ), MFMA ----------------
__global__ __launch_bounds__(256) void k4s_s(
    const float* __restrict__ x, const unsigned short* __restrict__ xh,
    const unsigned short* __restrict__ KMh,
    unsigned short* __restrict__ Sh, int use_xh)
{
  int tt = blockIdx.x, b = blockIdx.y;
  int tid = threadIdx.x;
  int lane = tid&63, w = tid>>6, m = lane&15, q = lane>>4;
  __shared__ unsigned short As[64*72];
  __shared__ unsigned short Bs[64*72];
  f32x4 acc[4];
  f32x4 z = {0.f,0.f,0.f,0.f};
#pragma unroll
  for (int nf=0;nf<4;nf++) acc[nf]=z;

  for (int k0=0;k0<DIN;k0+=64){
    uint4 bb[2];
#pragma unroll
    for (int v=0;v<2;v++){
      int idx=v*256+tid; int il=idx>>3, cc=idx&7;
      bb[v] = *(const uint4*)&KMh[((size_t)b*NCH+il)*DIN + k0 + cc*8];
    }
    if (use_xh){
      uint4 av[2];
#pragma unroll
      for (int v=0;v<2;v++){
        int idx=v*256+tid; int row=idx>>3, cc=idx&7;
        av[v] = *(const uint4*)&xh[((size_t)b*SEQ + (size_t)tt*64 + row)*DIN + k0 + cc*8];
      }
      __syncthreads();
#pragma unroll
      for (int v=0;v<2;v++){
        int idx=v*256+tid; int row=idx>>3, cc=idx&7;
        *(uint4*)&As[row*72 + cc*8] = av[v];
      }
    } else {
      float4 xa[4];
#pragma unroll
      for (int v=0;v<4;v++){
        int idx=v*256+tid; int row=idx>>4, cc=idx&15;
        xa[v] = *(const float4*)(x + ((size_t)b*SEQ + (size_t)tt*64 + row)*DIN + k0 + cc*4);
      }
      __syncthreads();
#pragma unroll
      for (int v=0;v<4;v++){
        int idx=v*256+tid; int row=idx>>4, cc=idx&15;
        store_bf4(&As[row*72 + cc*4], xa[v]);
      }
    }
#pragma unroll
    for (int v=0;v<2;v++){
      int idx=v*256+tid; int il=idx>>3, cc=idx&7;
      *(uint4*)&Bs[il*72 + cc*8] = bb[v];
    }
    __syncthreads();
#pragma unroll
    for (int kk=0;kk<2;kk++){
      bh8_t af = *(bh8_t*)&As[(w*16+m)*72 + kk*32 + q*8];
#pragma unroll
      for (int nf=0;nf<4;nf++){
        bh8_t bf_ = *(bh8_t*)&Bs[(nf*16+m)*72 + kk*32 + q*8];
        acc[nf] = __builtin_amdgcn_mfma_f32_16x16x32_bf16(af, bf_, acc[nf], 0,0,0);
      }
    }
  }
#pragma unroll
  for (int nf=0;nf<4;nf++)
#pragma unroll
    for (int r=0;r<4;r++)
      Sh[((size_t)b*SEQ + (size_t)tt*64 + w*16 + q*4 + r)*NCH + nf*16 + m] = f2bf(acc[nf][r]);
}

// ---------------- K4: out tile 64x256, MFMA ----------------
__global__ __launch_bounds__(256) void k4_out(
    const float* __restrict__ x, const unsigned short* __restrict__ xh,
    const unsigned short* __restrict__ M0h,
    const unsigned short* __restrict__ Sh, const unsigned short* __restrict__ UQTh,
    const float* __restrict__ P, float* __restrict__ out, int use_xh)
{
  int ot = blockIdx.x, j = blockIdx.y, b = blockIdx.z;
  int tid = threadIdx.x;
  int lane = tid&63, w = tid>>6, m = lane&15, q = lane>>4;
  int O0 = ot*256;
  __shared__ unsigned short As[64*72];
  __shared__ unsigned short Bs[256*72];
  f32x4 acc[16];
  f32x4 z = {0.f,0.f,0.f,0.f};
#pragma unroll
  for (int nf=0;nf<16;nf++) acc[nf]=z;

  // correction: masked S tile into As, UQT slice into Bs
  for (int idx=tid; idx<64*64; idx+=256){
    int t = idx>>6, i = idx&63;
    As[t*72+i] = (i<j) ? Sh[((size_t)b*SEQ + (size_t)j*64 + t)*NCH + i] : (unsigned short)0;
  }
#pragma unroll
  for (int v=0; v<8; v++){
    int idx = v*256+tid;
    int ol = idx>>3, cc = idx&7;
    *(uint4*)&Bs[ol*72 + cc*8] = *(const uint4*)&UQTh[((size_t)b*DOUT + O0+ol)*NCH + cc*8];
  }
  __syncthreads();
#pragma unroll
  for (int kk=0;kk<2;kk++){
    bh8_t af = *(bh8_t*)&As[(w*16+m)*72 + kk*32 + q*8];
#pragma unroll
    for (int nf=0;nf<16;nf++){
      bh8_t bf_ = *(bh8_t*)&Bs[(nf*16+m)*72 + kk*32 + q*8];
      acc[nf] = __builtin_amdgcn_mfma_f32_16x16x32_bf16(af, bf_, acc[nf], 0,0,0);
    }
  }

  // main GEMM: Xc @ M0h^T (256-wide O slice)
  for (int k0=0;k0<DIN;k0+=64){
    uint4 bb[8];
#pragma unroll
    for (int v=0;v<8;v++){
      int idx=v*256+tid; int ol=idx>>3, cc=idx&7;
      bb[v] = *(const uint4*)&M0h[(size_t)(O0+ol)*DIN + k0 + cc*8];
    }
    if (use_xh){
      uint4 av[2];
#pragma unroll
      for (int v=0;v<2;v++){
        int idx=v*256+tid; int row=idx>>3, cc=idx&7;
        av[v] = *(const uint4*)&xh[((size_t)b*SEQ + (size_t)j*64 + row)*DIN + k0 + cc*8];
      }
      __syncthreads();
#pragma unroll
      for (int v=0;v<2;v++){
        int idx=v*256+tid; int row=idx>>3, cc=idx&7;
        *(uint4*)&As[row*72 + cc*8] = av[v];
      }
    } else {
      float4 xa[4];
#pragma unroll
      for (int v=0;v<4;v++){
        int idx=v*256+tid; int row=idx>>4, cc=idx&15;
        xa[v] = *(const float4*)(x + ((size_t)b*SEQ + (size_t)j*64 + row)*DIN + k0 + cc*4);
      }
      __syncthreads();
#pragma unroll
      for (int v=0;v<4;v++){
        int idx=v*256+tid; int row=idx>>4, cc=idx&15;
        store_bf4(&As[row*72 + cc*4], xa[v]);
      }
    }
#pragma unroll
    for (int v=0;v<8;v++){
      int idx=v*256+tid; int ol=idx>>3, cc=idx&7;
      *(uint4*)&Bs[ol*72 + cc*8] = bb[v];
    }
    __syncthreads();
#pragma unroll
    for (int kk=0;kk<2;kk++){
      bh8_t af = *(bh8_t*)&As[(w*16+m)*72 + kk*32 + q*8];
#pragma unroll
      for (int nf=0;nf<16;nf++){
        bh8_t bf_ = *(bh8_t*)&Bs[(nf*16+m)*72 + kk*32 + q*8];
        acc[nf] = __builtin_amdgcn_mfma_f32_16x16x32_bf16(af, bf_, acc[nf], 0,0,0);
      }
    }
  }

  float p = P[b*65 + j];
#pragma unroll
  for (int nf=0;nf<16;nf++)
#pragma unroll
    for (int r=0;r<4;r++)
      out[((size_t)b*SEQ + (size_t)j*64 + w*16 + q*4 + r)*DOUT + O0 + nf*16 + m] = p*acc[nf][r];
}

// ---------------- K5: M_fin = p64*(M0 + sum_i q_i AU_i km_i^T) ----------------
__global__ __launch_bounds__(256) void k5_mfin(
    const float* __restrict__ M0, const float* __restrict__ KM,
    const float* __restrict__ AU, const float* __restrict__ P, const float* __restrict__ Q,
    float* __restrict__ Mout)
{
  int ob = blockIdx.x, b = blockIdx.y;
  int tid = threadIdx.x;
  __shared__ float uo[64][8];
  for (int idx=tid; idx<512; idx+=256){
    int i = idx>>3, oo = idx&7;
    uo[i][oo] = Q[b*NCH+i] * AU[((size_t)b*NCH+i)*DOUT + ob*8+oo];
  }
  __syncthreads();
  float p64 = P[b*65+NCH];
  float acc[2][8];
#pragma unroll
  for (int h=0;h<2;h++)
#pragma unroll
    for (int oo=0;oo<8;oo++) acc[h][oo]=0.f;
  int d0 = tid, d1 = tid+256;
  for (int i=0;i<64;i++){
    float k0 = KM[((size_t)b*NCH+i)*DIN + d0];
    float k1 = KM[((size_t)b*NCH+i)*DIN + d1];
#pragma unroll
    for (int oo=0;oo<8;oo++){
      float u = uo[i][oo];
      acc[0][oo] += u*k0;
      acc[1][oo] += u*k1;
    }
  }
#pragma unroll
  for (int oo=0;oo<8;oo++){
    int o = ob*8+oo;
    Mout[((size_t)b*DOUT + o)*DIN + d0] = p64*(M0[(size_t)o*DIN+d0] + acc[0][oo]);
    Mout[((size_t)b*DOUT + o)*DIN + d1] = p64*(M0[(size_t)o*DIN+d1] + acc[1][oo]);
  }
}

// ---------------- launch ----------------
extern "C" void kernel_launch(void* const* d_in, const int* in_sizes, int n_in,
                              void* d_out, int out_size, void* d_ws, size_t ws_size,
                              hipStream_t stream) {
  const float* x       = (const float*)d_in[0];
  const float* M0      = (const float*)d_in[1];
  const float* eta_w   = (const float*)d_in[2];
  const float* eta_b   = (const float*)d_in[3];
  const float* alpha_w = (const float*)d_in[4];
  const float* alpha_b = (const float*)d_in[5];
  const float* gate_w  = (const float*)d_in[6];
  const float* gate_b  = (const float*)d_in[7];
  float* out = (float*)d_out;

  float* ws = (float*)d_ws;
  // fp32 region
  float* KM   = ws;                    // 262144
  float* Dv   = KM   + 262144;
  float* G0   = Dv   + 262144;
  float* H0   = G0   + 262144;
  float* AU   = H0   + 262144;
  float* KMD  = AU   + 262144;         // 32768
  float* KMKM = KMD  + 32768;          // 32768
  float* C1   = KMKM + 32768;          // 512
  float* C2   = C1   + 512;
  float* KM2  = C2   + 512;
  float* Q    = KM2  + 512;
  float* DUW  = Q    + 512;            // 1024
  float* DUU  = DUW  + 1024;           // 1024
  float* P    = DUU  + 1024;           // 1024 (8*65 used)
  // bf16 region
  unsigned short* M0h  = (unsigned short*)(P + 1024);      // 262144 shorts
  unsigned short* KMh  = M0h  + 262144;                    // 262144
  unsigned short* Sh   = KMh  + 262144;                    // 2097152
  unsigned short* UQTh = Sh   + 2097152;                   // 262144
  unsigned short* xh   = UQTh + 262144;                    // 16777216 (optional)

  size_t base_bytes = (size_t)((char*)xh - (char*)d_ws);
  size_t need_xh = base_bytes + (size_t)16777216*2;
  int use_xh = (ws_size >= need_xh) ? 1 : 0;
  unsigned short* xh_arg = use_xh ? xh : (unsigned short*)0;

  k0_m0h<<<dim3(256), 256, 0, stream>>>(M0, M0h);
  k1_stats<<<dim3(NCH, NB), 256, 0, stream>>>(x, eta_w, eta_b, alpha_w, alpha_b,
                                              gate_w, gate_b, KM, Dv, KMh, C1, C2, KM2, Q, xh_arg);
  k2_g0h0<<<dim3(NCH, NB), 256, 0, stream>>>(KM, Dv, M0, G0, H0);
  k2b_gram<<<dim3(NCH, NB), 256, 0, stream>>>(KM, Dv, KMD, KMKM);
  k4s_s<<<dim3(SEQ/64, NB), 256, 0, stream>>>(x, xh, KMh, Sh, use_xh);
  k3a_au<<<dim3(2, NB), 256, 0, stream>>>(G0, H0, KMD, KMKM, Q, AU, UQTh, DUW, DUU);
  k3c_chain<<<dim3(NB), 256, 0, stream>>>(M0, C1, C2, KM2, DUW, DUU, P);
  k4_out<<<dim3(2, NCH, NB), 256, 0, stream>>>(x, xh, M0h, Sh, UQTh, P, out, use_xh);
  k5_mfin<<<dim3(64, NB), 256, 0, stream>>>(M0, KM, AU, P, Q, out + (size_t)NB*SEQ*DOUT);
}

// Round 5
// 494.053 us; speedup vs baseline: 1.4265x; 1.0351x over previous
//
#include <hip/hip_runtime.h>
#include <math.h>

#define DIN  512
#define DOUT 512
#define CHK  64
#define NCH  64
#define NB   8
#define SEQ  4096

typedef short bh8_t __attribute__((ext_vector_type(8)));
typedef float f32x4 __attribute__((ext_vector_type(4)));

__device__ __forceinline__ float sigmoidf_(float z){ return 1.0f/(1.0f+__expf(-z)); }

__device__ __forceinline__ unsigned short f2bf(float f){
  unsigned u = __float_as_uint(f);
  unsigned r = (u + 0x7fffu + ((u>>16)&1u)) >> 16;
  return (unsigned short)r;
}
__device__ __forceinline__ void store_bf4(unsigned short* p, float4 v){
  uint2 u;
  u.x = (unsigned)f2bf(v.x) | ((unsigned)f2bf(v.y)<<16);
  u.y = (unsigned)f2bf(v.z) | ((unsigned)f2bf(v.w)<<16);
  *(uint2*)p = u;
}

// ---------------- K0: M0 -> bf16 ----------------
__global__ __launch_bounds__(256) void k0_m0h(const float* __restrict__ M0, unsigned short* __restrict__ M0h){
  int idx = (blockIdx.x*256 + threadIdx.x)*4;
  float4 v = *(const float4*)(M0+idx);
  store_bf4(M0h+idx, v);
}

// ---------------- K1: per-(batch,chunk) statistics (+ x -> bf16) ----------------
__global__ __launch_bounds__(256) void k1_stats(
    const float* __restrict__ x,
    const float* __restrict__ eta_w, const float* __restrict__ eta_b,
    const float* __restrict__ alpha_w, const float* __restrict__ alpha_b,
    const float* __restrict__ gate_w, const float* __restrict__ gate_b,
    float* __restrict__ KM, float* __restrict__ Dv, unsigned short* __restrict__ KMh,
    float* __restrict__ C1, float* __restrict__ C2, float* __restrict__ KM2, float* __restrict__ Q,
    unsigned short* __restrict__ xh)
{
  int j = blockIdx.x, b = blockIdx.y;
  const float* xc = x + ((size_t)b*SEQ + (size_t)j*CHK) * DIN;
  int tid = threadIdx.x;
  int wave = tid >> 6, lane = tid & 63;

  float km_acc[8], xb_acc[8];
#pragma unroll
  for (int k=0;k<8;k++){ km_acc[k]=0.f; xb_acc[k]=0.f; }
  float eta_sum = 0.f, alpha_sum = 0.f;
  float ew[8], aw[8];
#pragma unroll
  for (int k=0;k<8;k++){ ew[k]=eta_w[lane*8+k]; aw[k]=alpha_w[lane*8+k]; }

  for (int tt=0; tt<16; tt++){
    int t = wave*16 + tt;
    const float* xr = xc + (size_t)t*DIN + lane*8;
    float v[8];
#pragma unroll
    for (int k=0;k<8;k++) v[k]=xr[k];
    if (xh){
      uint4 hv;
      hv.x = (unsigned)f2bf(v[0]) | ((unsigned)f2bf(v[1])<<16);
      hv.y = (unsigned)f2bf(v[2]) | ((unsigned)f2bf(v[3])<<16);
      hv.z = (unsigned)f2bf(v[4]) | ((unsigned)f2bf(v[5])<<16);
      hv.w = (unsigned)f2bf(v[6]) | ((unsigned)f2bf(v[7])<<16);
      *(uint4*)&xh[((size_t)b*SEQ + (size_t)j*CHK + t)*DIN + lane*8] = hv;
    }
    float pe=0.f, pa=0.f, pn=0.f;
#pragma unroll
    for (int k=0;k<8;k++){ pe += v[k]*ew[k]; pa += v[k]*aw[k]; pn += v[k]*v[k]; }
#pragma unroll
    for (int off=32; off; off>>=1){
      pe += __shfl_xor(pe, off);
      pa += __shfl_xor(pa, off);
      pn += __shfl_xor(pn, off);
    }
    float inv = 1.0f / fmaxf(sqrtf(pn), 1e-5f);
    eta_sum   += sigmoidf_(pe + eta_b[0]);
    alpha_sum += sigmoidf_(pa + alpha_b[0]);
#pragma unroll
    for (int k=0;k<8;k++){ km_acc[k] += v[k]*inv; xb_acc[k] += v[k]; }
  }

  __shared__ float sKM[4][DIN];
  __shared__ float sXB[4][DIN];
  __shared__ float sEA[4][2];
  __shared__ float sred[4][2];
#pragma unroll
  for (int k=0;k<8;k++){ sKM[wave][lane*8+k]=km_acc[k]; sXB[wave][lane*8+k]=xb_acc[k]; }
  if (lane==0){ sEA[wave][0]=eta_sum; sEA[wave][1]=alpha_sum; }
  __syncthreads();

  float gpart=0.f, km2part=0.f;
  float kmv[2], dvv[2];
#pragma unroll
  for (int k=0;k<2;k++){
    int d = tid*2+k;
    float km = (sKM[0][d]+sKM[1][d]+sKM[2][d]+sKM[3][d]) * (1.0f/64.0f);
    float xb = (sXB[0][d]+sXB[1][d]+sXB[2][d]+sXB[3][d]) * (1.0f/64.0f);
    kmv[k]=km; dvv[k]=xb-km;
    gpart  += km * gate_w[d];
    km2part+= km * km;
  }
#pragma unroll
  for (int off=32; off; off>>=1){
    gpart   += __shfl_xor(gpart, off);
    km2part += __shfl_xor(km2part, off);
  }
  if (lane==0){ sred[wave][0]=gpart; sred[wave][1]=km2part; }
  __syncthreads();

  size_t base = ((size_t)b*NCH + j)*DIN;
#pragma unroll
  for (int k=0;k<2;k++){
    int d = tid*2+k;
    KM[base+d]=kmv[k];
    Dv[base+d]=dvv[k];
    KMh[base+d]=f2bf(kmv[k]);
  }
  if (tid==0){
    float gdot = sred[0][0]+sred[1][0]+sred[2][0]+sred[3][0];
    float km2  = sred[0][1]+sred[1][1]+sred[2][1]+sred[3][1];
    float etam = (sEA[0][0]+sEA[1][0]+sEA[2][0]+sEA[3][0]) * (1.0f/64.0f);
    float alpm = (sEA[0][1]+sEA[1][1]+sEA[2][1]+sEA[3][1]) * (1.0f/64.0f);
    float eta   = 0.2f * etam;
    float alpha = 0.5f + 0.5f * alpm;
    float gate  = sigmoidf_(gdot + gate_b[0]);
    float c1 = gate*alpha + 1.0f - gate;
    float c2 = gate*eta;
    C1[b*NCH+j]  = c1;
    C2[b*NCH+j]  = c2;
    KM2[b*NCH+j] = km2;
    Q[b*NCH+j]   = c2/c1;
  }
}

// ---------------- K2: G0 = D @ M0^T, H0 = KM @ M0^T (o split in halves) ----------------
__global__ __launch_bounds__(256) void k2_g0h0(
    const float* __restrict__ KM, const float* __restrict__ Dv,
    const float* __restrict__ M0, float* __restrict__ G0, float* __restrict__ H0)
{
  int j = blockIdx.x, b = blockIdx.y, half = blockIdx.z;
  __shared__ float sD[DIN], sK[DIN];
  int tid = threadIdx.x;
  size_t base = ((size_t)b*NCH+j)*DIN;
  for (int d=tid; d<DIN; d+=256){ sD[d]=Dv[base+d]; sK[d]=KM[base+d]; }
  __syncthreads();
  int o = half*256 + tid;
  const float* mr = M0 + (size_t)o*DIN;
  float ag=0.f, ah=0.f;
  for (int d=0; d<DIN; d+=4){
    float4 m = *(const float4*)(mr+d);
    ag += m.x*sD[d] + m.y*sD[d+1] + m.z*sD[d+2] + m.w*sD[d+3];
    ah += m.x*sK[d] + m.y*sK[d+1] + m.z*sK[d+2] + m.w*sK[d+3];
  }
  G0[base+o]=ag; H0[base+o]=ah;
}

// ---------------- K2b: Gram matrices (512 threads, 8 waves) ----------------
__global__ __launch_bounds__(512) void k2b_gram(
    const float* __restrict__ KM, const float* __restrict__ Dv,
    float* __restrict__ KMD, float* __restrict__ KMKM)
{
  int i = blockIdx.x, b = blockIdx.y;
  __shared__ float sKi[DIN];
  int tid = threadIdx.x;
  const float* kmi = KM + ((size_t)b*NCH+i)*DIN;
  for (int d=tid; d<DIN; d+=512) sKi[d]=kmi[d];
  __syncthreads();
  int wave = tid>>6, lane = tid&63;
  for (int j=wave; j<NCH; j+=8){
    const float* dj = Dv + ((size_t)b*NCH+j)*DIN;
    const float* kj = KM + ((size_t)b*NCH+j)*DIN;
    float pd=0.f, pk=0.f;
#pragma unroll
    for (int k=0;k<8;k++){
      int d = lane + k*64;
      pd += sKi[d]*dj[d];
      pk += sKi[d]*kj[d];
    }
#pragma unroll
    for (int off=32; off; off>>=1){ pd += __shfl_xor(pd,off); pk += __shfl_xor(pk,off); }
    if (lane==0){
      KMD [((size_t)b*NCH+i)*NCH + j] = pd;
      KMKM[((size_t)b*NCH+i)*NCH + j] = pk;
    }
  }
}

// ---------------- K3: fused recurrence + dots + UQT pack + p-chain ----------------
// grid (NB), 512 threads; d = tid
__global__ __launch_bounds__(512) void k3_fused(
    const float* __restrict__ M0,
    const float* __restrict__ G0, const float* __restrict__ H0,
    const float* __restrict__ KMD, const float* __restrict__ KMKM,
    const float* __restrict__ Q,
    const float* __restrict__ C1, const float* __restrict__ C2, const float* __restrict__ KM2,
    float* __restrict__ AU, unsigned short* __restrict__ UQTh, float* __restrict__ P)
{
  int b = blockIdx.x;
  int tid = threadIdx.x, wave = tid>>6, lane = tid&63;
  __shared__ float scM[4096], scW[4096];
  __shared__ float sq[64];
  __shared__ float sdots[64][8][2];
  __shared__ float sred[8];

  for (int idx=tid; idx<4096; idx+=512){
    int i=idx>>6, jj=idx&63;
    float qv = Q[b*NCH+i];
    scM[idx] = qv*KMD [((size_t)b*NCH+i)*NCH+jj];
    scW[idx] = qv*KMKM[((size_t)b*NCH+i)*NCH+jj];
  }
  if (tid<64) sq[tid] = Q[b*NCH+tid];

  // F0 = ||M0||^2 partials
  float f0p = 0.f;
  const float4* m4 = (const float4*)M0;
  for (int i=tid; i<(DOUT*DIN)/4; i+=512){
    float4 v = m4[i];
    f0p += v.x*v.x + v.y*v.y + v.z*v.z + v.w*v.w;
  }
#pragma unroll
  for (int off=32; off; off>>=1) f0p += __shfl_xor(f0p, off);
  if (lane==0) sred[wave]=f0p;
  __syncthreads();

  // preload all 64 G0 values
  float au[NCH];
  size_t gb = (size_t)b*NCH*DOUT + tid;
#pragma unroll
  for (int j=0;j<NCH;j++) au[j] = G0[gb + (size_t)j*DOUT];

  // in-register triangular recurrence
#pragma unroll
  for (int j=0;j<NCH;j++){
    float a = au[j];
#pragma unroll
    for (int i=0;i<j;i++) a += scM[i*64+j]*au[i];
    au[j]=a;
  }
#pragma unroll
  for (int j=0;j<NCH;j++) AU[gb + (size_t)j*DOUT] = au[j];

  // UQT pack: row d = tid, 64 bf16 (q_i * au_i)
#pragma unroll
  for (int g=0; g<8; g++){
    uint4 hv;
    hv.x = (unsigned)f2bf(au[g*8+0]*sq[g*8+0]) | ((unsigned)f2bf(au[g*8+1]*sq[g*8+1])<<16);
    hv.y = (unsigned)f2bf(au[g*8+2]*sq[g*8+2]) | ((unsigned)f2bf(au[g*8+3]*sq[g*8+3])<<16);
    hv.z = (unsigned)f2bf(au[g*8+4]*sq[g*8+4]) | ((unsigned)f2bf(au[g*8+5]*sq[g*8+5])<<16);
    hv.w = (unsigned)f2bf(au[g*8+6]*sq[g*8+6]) | ((unsigned)f2bf(au[g*8+7]*sq[g*8+7])<<16);
    *(uint4*)&UQTh[((size_t)b*DOUT + tid)*NCH + g*8] = hv;
  }

  // phase 2: w_j and dot partials
#pragma unroll
  for (int j=0;j<NCH;j++){
    float w = H0[gb + (size_t)j*DOUT];
#pragma unroll
    for (int i=0;i<j;i++) w += scW[i*64+j]*au[i];
    float s1 = au[j]*w, s2 = au[j]*au[j];
#pragma unroll
    for (int off=32; off; off>>=1){ s1+=__shfl_xor(s1,off); s2+=__shfl_xor(s2,off); }
    if (lane==0){ sdots[j][wave][0]=s1; sdots[j][wave][1]=s2; }
  }
  __syncthreads();

  if (tid==0){
    float F = 0.f;
#pragma unroll
    for (int w2=0;w2<8;w2++) F += sred[w2];
    float p = 1.f;
    P[b*65+0] = 1.f;
    for (int j=0;j<NCH;j++){
      float uw=0.f, uu=0.f;
#pragma unroll
      for (int w2=0;w2<8;w2++){ uw += sdots[j][w2][0]; uu += sdots[j][w2][1]; }
      float c1 = C1[b*NCH+j], c2 = C2[b*NCH+j], km2 = KM2[b*NCH+j];
      uw *= p*p; uu *= p*p;
      float Fnew = c1*c1*F + 2.f*c1*c2*uw + c2*c2*uu*km2;
      float scale = fminf(30.0f/(sqrtf(Fnew)+1e-6f), 1.0f);
      F = scale*scale*Fnew;
      p = scale*c1*p;
      P[b*65+j+1] = p;
    }
  }
}

// ---------------- K4s: Sh = bf16( X @ KM^T ), MFMA, coalesced epilogue ----------------
__global__ __launch_bounds__(256) void k4s_s(
    const float* __restrict__ x, const unsigned short* __restrict__ xh,
    const unsigned short* __restrict__ KMh,
    unsigned short* __restrict__ Sh, int use_xh)
{
  int tt = blockIdx.x, b = blockIdx.y;
  int tid = threadIdx.x;
  int lane = tid&63, w = tid>>6, m = lane&15, q = lane>>4;
  __shared__ unsigned short As[64*72];
  __shared__ unsigned short Bs[64*72];
  f32x4 acc[4];
  f32x4 z = {0.f,0.f,0.f,0.f};
#pragma unroll
  for (int nf=0;nf<4;nf++) acc[nf]=z;

  for (int k0=0;k0<DIN;k0+=64){
    uint4 bb[2];
#pragma unroll
    for (int v=0;v<2;v++){
      int idx=v*256+tid; int il=idx>>3, cc=idx&7;
      bb[v] = *(const uint4*)&KMh[((size_t)b*NCH+il)*DIN + k0 + cc*8];
    }
    if (use_xh){
      uint4 av[2];
#pragma unroll
      for (int v=0;v<2;v++){
        int idx=v*256+tid; int row=idx>>3, cc=idx&7;
        av[v] = *(const uint4*)&xh[((size_t)b*SEQ + (size_t)tt*64 + row)*DIN + k0 + cc*8];
      }
      __syncthreads();
#pragma unroll
      for (int v=0;v<2;v++){
        int idx=v*256+tid; int row=idx>>3, cc=idx&7;
        *(uint4*)&As[row*72 + cc*8] = av[v];
      }
    } else {
      float4 xa[4];
#pragma unroll
      for (int v=0;v<4;v++){
        int idx=v*256+tid; int row=idx>>4, cc=idx&15;
        xa[v] = *(const float4*)(x + ((size_t)b*SEQ + (size_t)tt*64 + row)*DIN + k0 + cc*4);
      }
      __syncthreads();
#pragma unroll
      for (int v=0;v<4;v++){
        int idx=v*256+tid; int row=idx>>4, cc=idx&15;
        store_bf4(&As[row*72 + cc*4], xa[v]);
      }
    }
#pragma unroll
    for (int v=0;v<2;v++){
      int idx=v*256+tid; int il=idx>>3, cc=idx&7;
      *(uint4*)&Bs[il*72 + cc*8] = bb[v];
    }
    __syncthreads();
#pragma unroll
    for (int kk=0;kk<2;kk++){
      bh8_t af = *(bh8_t*)&As[(w*16+m)*72 + kk*32 + q*8];
#pragma unroll
      for (int nf=0;nf<4;nf++){
        bh8_t bf_ = *(bh8_t*)&Bs[(nf*16+m)*72 + kk*32 + q*8];
        acc[nf] = __builtin_amdgcn_mfma_f32_16x16x32_bf16(af, bf_, acc[nf], 0,0,0);
      }
    }
  }
  // per-wave transpose in LDS (wave w owns rows 16w..16w+15), coalesced stores
  __syncthreads();
  unsigned short* tb = As + w*16*72;
#pragma unroll
  for (int nf=0;nf<4;nf++)
#pragma unroll
    for (int r=0;r<4;r++)
      tb[(q*4+r)*72 + nf*16 + m] = f2bf(acc[nf][r]);
#pragma unroll
  for (int v=0;v<2;v++){
    int idx = v*64 + lane;
    int row = idx>>3, c8 = idx&7;
    uint4 vv = *(uint4*)&tb[row*72 + c8*8];
    *(uint4*)&Sh[((size_t)b*SEQ + (size_t)tt*64 + w*16 + row)*NCH + c8*8] = vv;
  }
}

// ---------------- K4: out tile 64x128, MFMA, coalesced epilogue ----------------
__global__ __launch_bounds__(256) void k4_out(
    const float* __restrict__ x, const unsigned short* __restrict__ xh,
    const unsigned short* __restrict__ M0h,
    const unsigned short* __restrict__ Sh, const unsigned short* __restrict__ UQTh,
    const float* __restrict__ P, float* __restrict__ out, int use_xh)
{
  int ot = blockIdx.x, j = blockIdx.y, b = blockIdx.z;
  int tid = threadIdx.x;
  int lane = tid&63, w = tid>>6, m = lane&15, q = lane>>4;
  int O0 = ot*128;
  // pool: staging As(64*72 shorts) + Bs(128*72 shorts) = 27648 B; epilogue 4*16*132 floats = 33792 B
  __shared__ __align__(16) char pool[33792];
  unsigned short* As = (unsigned short*)pool;
  unsigned short* Bs = (unsigned short*)pool + 64*72;
  float* ep = (float*)pool;
  f32x4 acc[8];
  f32x4 z = {0.f,0.f,0.f,0.f};
#pragma unroll
  for (int nf=0;nf<8;nf++) acc[nf]=z;
  float p = P[b*65 + j];

  // correction: masked S tile into As, UQT slice into Bs
  for (int idx=tid; idx<64*64; idx+=256){
    int t = idx>>6, i = idx&63;
    As[t*72+i] = (i<j) ? Sh[((size_t)b*SEQ + (size_t)j*64 + t)*NCH + i] : (unsigned short)0;
  }
#pragma unroll
  for (int v=0; v<4; v++){
    int idx = v*256+tid;
    int ol = idx>>3, cc = idx&7;
    *(uint4*)&Bs[ol*72 + cc*8] = *(const uint4*)&UQTh[((size_t)b*DOUT + O0+ol)*NCH + cc*8];
  }
  __syncthreads();
#pragma unroll
  for (int kk=0;kk<2;kk++){
    bh8_t af = *(bh8_t*)&As[(w*16+m)*72 + kk*32 + q*8];
#pragma unroll
    for (int nf=0;nf<8;nf++){
      bh8_t bf_ = *(bh8_t*)&Bs[(nf*16+m)*72 + kk*32 + q*8];
      acc[nf] = __builtin_amdgcn_mfma_f32_16x16x32_bf16(af, bf_, acc[nf], 0,0,0);
    }
  }

  // main GEMM: Xc @ M0h^T (128-wide O slice)
  for (int k0=0;k0<DIN;k0+=64){
    uint4 bb[4];
#pragma unroll
    for (int v=0;v<4;v++){
      int idx=v*256+tid; int ol=idx>>3, cc=idx&7;
      bb[v] = *(const uint4*)&M0h[(size_t)(O0+ol)*DIN + k0 + cc*8];
    }
    if (use_xh){
      uint4 av[2];
#pragma unroll
      for (int v=0;v<2;v++){
        int idx=v*256+tid; int row=idx>>3, cc=idx&7;
        av[v] = *(const uint4*)&xh[((size_t)b*SEQ + (size_t)j*64 + row)*DIN + k0 + cc*8];
      }
      __syncthreads();
#pragma unroll
      for (int v=0;v<2;v++){
        int idx=v*256+tid; int row=idx>>3, cc=idx&7;
        *(uint4*)&As[row*72 + cc*8] = av[v];
      }
    } else {
      float4 xa[4];
#pragma unroll
      for (int v=0;v<4;v++){
        int idx=v*256+tid; int row=idx>>4, cc=idx&15;
        xa[v] = *(const float4*)(x + ((size_t)b*SEQ + (size_t)j*64 + row)*DIN + k0 + cc*4);
      }
      __syncthreads();
#pragma unroll
      for (int v=0;v<4;v++){
        int idx=v*256+tid; int row=idx>>4, cc=idx&15;
        store_bf4(&As[row*72 + cc*4], xa[v]);
      }
    }
#pragma unroll
    for (int v=0;v<4;v++){
      int idx=v*256+tid; int ol=idx>>3, cc=idx&7;
      *(uint4*)&Bs[ol*72 + cc*8] = bb[v];
    }
    __syncthreads();
#pragma unroll
    for (int kk=0;kk<2;kk++){
      bh8_t af = *(bh8_t*)&As[(w*16+m)*72 + kk*32 + q*8];
#pragma unroll
      for (int nf=0;nf<8;nf++){
        bh8_t bf_ = *(bh8_t*)&Bs[(nf*16+m)*72 + kk*32 + q*8];
        acc[nf] = __builtin_amdgcn_mfma_f32_16x16x32_bf16(af, bf_, acc[nf], 0,0,0);
      }
    }
  }

  // epilogue: per-wave transpose (wave w owns rows 16w..16w+15) -> coalesced stores
  __syncthreads();
  float* epw = ep + w*16*132;
#pragma unroll
  for (int nf=0;nf<8;nf++)
#pragma unroll
    for (int r=0;r<4;r++)
      epw[(q*4+r)*132 + nf*16 + m] = p*acc[nf][r];
#pragma unroll
  for (int v=0;v<8;v++){
    int idx = v*64 + lane;
    int row = idx>>5, c4 = idx&31;
    float4 vv = *(float4*)&epw[row*132 + c4*4];
    *(float4*)&out[((size_t)b*SEQ + (size_t)j*64 + w*16 + row)*DOUT + O0 + c4*4] = vv;
  }
}

// ---------------- K5: M_fin = p64*(M0 + sum_i q_i AU_i km_i^T) ----------------
__global__ __launch_bounds__(256) void k5_mfin(
    const float* __restrict__ M0, const float* __restrict__ KM,
    const float* __restrict__ AU, const float* __restrict__ P, const float* __restrict__ Q,
    float* __restrict__ Mout)
{
  int ob = blockIdx.x, b = blockIdx.y;
  int tid = threadIdx.x;
  __shared__ float uo[64][8];
  for (int idx=tid; idx<512; idx+=256){
    int i = idx>>3, oo = idx&7;
    uo[i][oo] = Q[b*NCH+i] * AU[((size_t)b*NCH+i)*DOUT + ob*8+oo];
  }
  __syncthreads();
  float p64 = P[b*65+NCH];
  float acc[2][8];
#pragma unroll
  for (int h=0;h<2;h++)
#pragma unroll
    for (int oo=0;oo<8;oo++) acc[h][oo]=0.f;
  int d0 = tid, d1 = tid+256;
  for (int i=0;i<64;i++){
    float k0 = KM[((size_t)b*NCH+i)*DIN + d0];
    float k1 = KM[((size_t)b*NCH+i)*DIN + d1];
#pragma unroll
    for (int oo=0;oo<8;oo++){
      float u = uo[i][oo];
      acc[0][oo] += u*k0;
      acc[1][oo] += u*k1;
    }
  }
#pragma unroll
  for (int oo=0;oo<8;oo++){
    int o = ob*8+oo;
    Mout[((size_t)b*DOUT + o)*DIN + d0] = p64*(M0[(size_t)o*DIN+d0] + acc[0][oo]);
    Mout[((size_t)b*DOUT + o)*DIN + d1] = p64*(M0[(size_t)o*DIN+d1] + acc[1][oo]);
  }
}

// ---------------- launch ----------------
extern "C" void kernel_launch(void* const* d_in, const int* in_sizes, int n_in,
                              void* d_out, int out_size, void* d_ws, size_t ws_size,
                              hipStream_t stream) {
  const float* x       = (const float*)d_in[0];
  const float* M0      = (const float*)d_in[1];
  const float* eta_w   = (const float*)d_in[2];
  const float* eta_b   = (const float*)d_in[3];
  const float* alpha_w = (const float*)d_in[4];
  const float* alpha_b = (const float*)d_in[5];
  const float* gate_w  = (const float*)d_in[6];
  const float* gate_b  = (const float*)d_in[7];
  float* out = (float*)d_out;

  float* ws = (float*)d_ws;
  // fp32 region
  float* KM   = ws;                    // 262144
  float* Dv   = KM   + 262144;
  float* G0   = Dv   + 262144;
  float* H0   = G0   + 262144;
  float* AU   = H0   + 262144;
  float* KMD  = AU   + 262144;         // 32768
  float* KMKM = KMD  + 32768;          // 32768
  float* C1   = KMKM + 32768;          // 512
  float* C2   = C1   + 512;
  float* KM2  = C2   + 512;
  float* Q    = KM2  + 512;
  float* P    = Q    + 512;            // 1024 (8*65 used)
  // bf16 region
  unsigned short* M0h  = (unsigned short*)(P + 1024);      // 262144 shorts
  unsigned short* KMh  = M0h  + 262144;                    // 262144
  unsigned short* Sh   = KMh  + 262144;                    // 2097152
  unsigned short* UQTh = Sh   + 2097152;                   // 262144
  unsigned short* xh   = UQTh + 262144;                    // 16777216 (optional)

  size_t base_bytes = (size_t)((char*)xh - (char*)d_ws);
  size_t need_xh = base_bytes + (size_t)16777216*2;
  int use_xh = (ws_size >= need_xh) ? 1 : 0;
  unsigned short* xh_arg = use_xh ? xh : (unsigned short*)0;

  k0_m0h<<<dim3(256), 256, 0, stream>>>(M0, M0h);
  k1_stats<<<dim3(NCH, NB), 256, 0, stream>>>(x, eta_w, eta_b, alpha_w, alpha_b,
                                              gate_w, gate_b, KM, Dv, KMh, C1, C2, KM2, Q, xh_arg);
  k2_g0h0<<<dim3(NCH, NB, 2), 256, 0, stream>>>(KM, Dv, M0, G0, H0);
  k2b_gram<<<dim3(NCH, NB), 512, 0, stream>>>(KM, Dv, KMD, KMKM);
  k4s_s<<<dim3(SEQ/64, NB), 256, 0, stream>>>(x, xh, KMh, Sh, use_xh);
  k3_fused<<<dim3(NB), 512, 0, stream>>>(M0, G0, H0, KMD, KMKM, Q, C1, C2, KM2, AU, UQTh, P);
  k4_out<<<dim3(4, NCH, NB), 256, 0, stream>>>(x, xh, M0h, Sh, UQTh, P, out, use_xh);
  k5_mfin<<<dim3(64, NB), 256, 0, stream>>>(M0, KM, AU, P, Q, out + (size_t)NB*SEQ*DOUT);
}